// Round 15
// baseline (717.372 us; speedup 1.0000x reference)
//
#include <hip/hip_runtime.h>

// AttnBlock2D: GroupNorm -> fused QKV -> 1-head attention (hw=4096, dh=512) -> proj + residual
// R15 = R14 (660.9us) + S-GEMM on a hand-derived fine-phase 256^2 engine (gemm_s8p):
//       4 phases/K-tile, one stage-unit (A0/B0/B1/A1) issued per phase, per-wave frags
//       interleaved across tile halves so each quadrant needs only already-retired units;
//       uniform vmcnt(4) (never 0 mid-loop), 3 barriers/tile. QKV/PV/res = R14 verbatim.

#define BATCH 8
#define CCH 512
#define HWP 4096
#define NG 32

#define AS1 __attribute__((address_space(1)))
#define AS3 __attribute__((address_space(3)))

typedef __attribute__((ext_vector_type(8))) short s16x8;
typedef __attribute__((ext_vector_type(4))) float f32x4;

__device__ __forceinline__ unsigned short f2bf(float f) {
  union { float f; unsigned u; } v; v.f = f;
  return (unsigned short)((v.u + 0x7FFFu + ((v.u >> 16) & 1u)) >> 16);
}

// ---------------- weight convert f32 -> bf16 (4 matrices) + qkv bias concat ----------------
__global__ void cvt_w(const float* __restrict__ w0, const float* __restrict__ w1,
                      const float* __restrict__ w2, const float* __restrict__ w3,
                      const float* __restrict__ bq, const float* __restrict__ bk,
                      const float* __restrict__ bv,
                      unsigned short* __restrict__ out, float* __restrict__ bcat) {
  int i = blockIdx.x * 256 + threadIdx.x;
  const int n = CCH * CCH;
  if (i < CCH) {
    bcat[i]           = bq[i];
    bcat[CCH + i]     = bk[i];
    bcat[2 * CCH + i] = bv[i];
  }
  if (i < n) {
    out[i]         = f2bf(w0[i]);
    out[n + i]     = f2bf(w1[i]);
    out[2 * n + i] = f2bf(w2[i]);
    out[3 * n + i] = f2bf(w3[i]);
  }
}

// ---------------- GroupNorm stats: one block per (b,g) ----------------
__global__ void gn_stats(const float* __restrict__ x, float* __restrict__ stats) {
  const int bg = blockIdx.x;
  const float* base = x + (size_t)bg * (16 * HWP);
  float s = 0.f, sq = 0.f;
  for (int i = threadIdx.x; i < 16 * HWP / 4; i += 256) {
    float4 v = ((const float4*)base)[i];
    s += v.x + v.y + v.z + v.w;
    sq += v.x * v.x + v.y * v.y + v.z * v.z + v.w * v.w;
  }
  #pragma unroll
  for (int o = 32; o; o >>= 1) { s += __shfl_xor(s, o); sq += __shfl_xor(sq, o); }
  __shared__ float ls[4], lq[4];
  const int wv = threadIdx.x >> 6;
  if ((threadIdx.x & 63) == 0) { ls[wv] = s; lq[wv] = sq; }
  __syncthreads();
  if (threadIdx.x == 0) {
    s = ls[0] + ls[1] + ls[2] + ls[3];
    sq = lq[0] + lq[1] + lq[2] + lq[3];
    const float inv_n = 1.f / (16.f * HWP);
    float mean = s * inv_n;
    float var = sq * inv_n - mean * mean;
    stats[2 * bg] = mean;
    stats[2 * bg + 1] = rsqrtf(var + 1e-5f);
  }
}

// ---------------- GroupNorm apply + transpose -> h_t (hw, c) bf16 ----------------
__global__ void gn_apply(const float* __restrict__ x, const float* __restrict__ stats,
                         const float* __restrict__ scale, const float* __restrict__ bias,
                         unsigned short* __restrict__ ht) {
  const int p0 = blockIdx.x * 64, c0 = blockIdx.y * 64, b = blockIdx.z;
  const int tx = threadIdx.x & 63, ty = threadIdx.x >> 6;
  __shared__ unsigned short tile[64][65];
  #pragma unroll 4
  for (int j = 0; j < 16; ++j) {
    int cl = ty + j * 4;
    int c = c0 + cl;
    int g = c >> 4;
    float mean = stats[(b * NG + g) * 2];
    float rstd = stats[(b * NG + g) * 2 + 1];
    float v = x[((size_t)(b * CCH + c)) * HWP + p0 + tx];
    v = (v - mean) * rstd * scale[c] + bias[c];
    tile[cl][tx] = f2bf(v);
  }
  __syncthreads();
  #pragma unroll 4
  for (int j = 0; j < 16; ++j) {
    int pl = ty + j * 4;
    ht[((size_t)b * HWP + p0 + pl) * CCH + c0 + tx] = tile[tx][pl];
  }
}

// ---------------- NT GEMM (R3 engine): C = scale*A[M,K]*B[N,K]^T, 128x128, BK=64, dbuf ----------------
// MODE 0: bf16 out + biasCol; if Res!=null and n0>=1024, tile is V: transpose via LDS
//         bounce (pad 152) and write to vT (=Res, stride sRes).  (fused QKV+V^T)
// MODE 2: bf16 out, v / rowsum(A)         (PV with fused softmax denominator)
// MODE 3: f32 out, + biasRow + Res(prefetched to regs), coalesced epilogue (final proj)
template<int MODE>
__device__ __forceinline__ void gemm_body(
    const unsigned short* __restrict__ A, const unsigned short* __restrict__ Bm,
    void* __restrict__ Cm, const float* __restrict__ biasRow,
    const float* __restrict__ biasCol, const float* __restrict__ Res,
    int K, int lda, int ldb, int ldc, float scale,
    long long sA, long long sB, long long sC, long long sRes) {
  // --- bijective XCD swizzle ---
  const int nbx = gridDim.x, nby = gridDim.y;
  const int nb = nbx * nby * gridDim.z;
  int lin = (blockIdx.z * nby + blockIdx.y) * nbx + blockIdx.x;
  int bx, by, bz;
  if ((nb & 7) == 0) {
    int logical = (lin & 7) * (nb >> 3) + (lin >> 3);
    bx = logical % nbx;
    int t = logical / nbx;
    by = t % nby;
    bz = t / nby;
  } else { bx = blockIdx.x; by = blockIdx.y; bz = blockIdx.z; }

  const unsigned short* Ab = A + (size_t)bz * sA;
  const unsigned short* Bb = Bm + (size_t)bz * sB;
  const int m0 = by * 128, n0 = bx * 128;
  __shared__ __align__(16) unsigned short sm[2][2][128 * 64];  // [A/B][dbuf][tile]
  const int tid = threadIdx.x, wave = tid >> 6, lane = tid & 63;
  const int wr = (wave >> 1) * 64, wc = (wave & 1) * 64;
  const int lr = lane & 15, lkc = lane >> 4;
  f32x4 acc[4][4] = {};
  f32x4 acc_d[4] = {};                               // MODE 2: row-sum
  s16x8 bones;
  #pragma unroll
  for (int j = 0; j < 8; ++j) bones[j] = (short)0x3F80;  // bf16 1.0

  // MODE 3: prefetch the residual tile into registers (read hides under the K-loop)
  float4 xr[16];
  if (MODE == 3) {
    #pragma unroll
    for (int pass = 0; pass < 2; ++pass)
      #pragma unroll
      for (int i = 0; i < 8; ++i) {
        int idx = i * 256 + tid;
        int rrow = idx >> 5, c4 = (idx & 31) << 2;
        size_t gidx = (size_t)(m0 + pass * 64 + rrow) * ldc + (n0 + c4);
        xr[pass * 8 + i] = *(const float4*)&Res[(size_t)bz * sRes + gidx];
      }
  }

  const int chunkBase = wave * 64 + lane;
  int srow[4], sc8[4];
  #pragma unroll
  for (int it = 0; it < 4; ++it) {
    int chunk = it * 256 + chunkBase;
    srow[it] = chunk >> 3;
    sc8[it] = (((chunk & 7) ^ (srow[it] & 7)) * 8);
  }

  #define STAGE(buf, kt)                                                                 \
    { _Pragma("unroll")                                                                  \
      for (int it = 0; it < 4; ++it) {                                                   \
        __builtin_amdgcn_global_load_lds(                                                \
            (const AS1 unsigned int*)(Ab + (size_t)(m0 + srow[it]) * lda + (kt) + sc8[it]), \
            (AS3 unsigned int*)(&sm[0][buf][0] + (size_t)(it * 256 + wave * 64) * 8), 16, 0, 0); \
        __builtin_amdgcn_global_load_lds(                                                \
            (const AS1 unsigned int*)(Bb + (size_t)(n0 + srow[it]) * ldb + (kt) + sc8[it]), \
            (AS3 unsigned int*)(&sm[1][buf][0] + (size_t)(it * 256 + wave * 64) * 8), 16, 0, 0); \
      }                                                                                  \
    }

  STAGE(0, 0);
  __syncthreads();
  int cur = 0;
  for (int kt = 0; kt < K; kt += 64) {
    if (kt + 64 < K) STAGE(cur ^ 1, kt + 64);
    #pragma unroll
    for (int kk = 0; kk < 64; kk += 32) {
      const int jbase = (kk >> 3) + lkc;
      s16x8 af[4], bfv[4];
      #pragma unroll
      for (int m = 0; m < 4; ++m) {
        int r = wr + m * 16 + lr;
        af[m] = *(const s16x8*)&sm[0][cur][r * 64 + ((jbase ^ (r & 7)) << 3)];
      }
      #pragma unroll
      for (int n = 0; n < 4; ++n) {
        int r = wc + n * 16 + lr;
        bfv[n] = *(const s16x8*)&sm[1][cur][r * 64 + ((jbase ^ (r & 7)) << 3)];
      }
      #pragma unroll
      for (int m = 0; m < 4; ++m) {
        #pragma unroll
        for (int n = 0; n < 4; ++n)
          acc[m][n] = __builtin_amdgcn_mfma_f32_16x16x32_bf16(af[m], bfv[n], acc[m][n], 0, 0, 0);
        if (MODE == 2)
          acc_d[m] = __builtin_amdgcn_mfma_f32_16x16x32_bf16(af[m], bones, acc_d[m], 0, 0, 0);
      }
    }
    __syncthreads();
    cur ^= 1;
  }
  #undef STAGE

  const int r0 = (lane >> 4) * 4, ccol = lane & 15;
  if (MODE == 0 && Res != nullptr && n0 >= 1024) {
    // ---- V-block: transpose tile via LDS bounce (pad 152 -> 2-way banks) -> vT (b,c,p) ----
    unsigned short* lt = (unsigned short*)&sm[0][0][0];   // [128][152] bf16 (38 KB)
    #pragma unroll
    for (int m = 0; m < 4; ++m) {
      const int gm_l = wr + m * 16 + r0;                  // local p-row (mult of 4)
      #pragma unroll
      for (int n = 0; n < 4; ++n) {
        const int gn_l = wc + n * 16 + ccol;              // local o-col
        const float bc = biasCol ? biasCol[n0 + gn_l] : 0.f;
        union { unsigned short us[4]; uint2 u2; } pk;
        #pragma unroll
        for (int r = 0; r < 4; ++r) pk.us[r] = f2bf(acc[m][n][r] + bc);
        *(uint2*)&lt[gn_l * 152 + gm_l] = pk.u2;          // transposed: [o][p]
      }
    }
    __syncthreads();
    unsigned short* vout = (unsigned short*)Res;          // vT base
    const int c0v = n0 - 1024;
    #pragma unroll
    for (int i = 0; i < 8; ++i) {
      int idx = i * 256 + tid;
      int orow = idx >> 4, pc = (idx & 15) * 8;
      s16x8 v = *(const s16x8*)&lt[orow * 152 + pc];
      *(s16x8*)&vout[(size_t)bz * sRes + (size_t)(c0v + orow) * HWP + m0 + pc] = v;
    }
  } else if (MODE != 3) {
    #pragma unroll
    for (int m = 0; m < 4; ++m) {
      const int gm = m0 + wr + m * 16 + r0;
      float inv[4] = {1.f, 1.f, 1.f, 1.f};
      if (MODE == 2) {
        inv[0] = 1.f / acc_d[m][0];
        inv[1] = 1.f / acc_d[m][1];
        inv[2] = 1.f / acc_d[m][2];
        inv[3] = 1.f / acc_d[m][3];
      }
      #pragma unroll
      for (int n = 0; n < 4; ++n) {
        const int gn = n0 + wc + n * 16 + ccol;
        const float bc = (MODE == 0 && biasCol) ? biasCol[gn] : 0.f;
        #pragma unroll
        for (int r = 0; r < 4; ++r) {
          float val = acc[m][n][r];
          if (MODE == 0) val = val * scale + bc;
          if (MODE == 2) val = val * inv[r];
          size_t idx = (size_t)(gm + r) * ldc + gn;
          ((unsigned short*)Cm)[(size_t)bz * sC + idx] = f2bf(val);
        }
      }
    }
  } else {
    // f32 out: coalesced epilogue via LDS bounce; residual already in xr registers
    float* ft = (float*)&sm[0][0][0];
    float* Cf = (float*)Cm;
    #pragma unroll
    for (int pass = 0; pass < 2; ++pass) {
      __syncthreads();
      if ((wave >> 1) == pass) {
        #pragma unroll
        for (int m = 0; m < 4; ++m) {
          const int rl0 = m * 16 + (lane >> 4) * 4;
          #pragma unroll
          for (int n = 0; n < 4; ++n) {
            const int cl = wc + n * 16 + (lane & 15);
            #pragma unroll
            for (int r = 0; r < 4; ++r) {
              float val = acc[m][n][r];
              if (biasRow) val += biasRow[m0 + pass * 64 + rl0 + r];
              ft[(rl0 + r) * 132 + cl] = val;
            }
          }
        }
      }
      __syncthreads();
      #pragma unroll
      for (int i = 0; i < 8; ++i) {
        int idx = i * 256 + tid;
        int rrow = idx >> 5, c4 = (idx & 31) << 2;
        float4 v = *(const float4*)&ft[rrow * 132 + c4];
        const float4 rv = xr[pass * 8 + i];
        v.x += rv.x; v.y += rv.y; v.z += rv.z; v.w += rv.w;
        size_t gidx = (size_t)(m0 + pass * 64 + rrow) * ldc + (n0 + c4);
        *(float4*)&Cf[(size_t)bz * sC + gidx] = v;
      }
    }
  }
}

#define GEMM_ARGS const unsigned short* A, const unsigned short* Bm, void* Cm,            \
                  const float* biasRow, const float* biasCol, const float* Res,            \
                  int K, int lda, int ldb, int ldc, float scale,                           \
                  long long sA, long long sB, long long sC, long long sRes
#define GEMM_PASS A, Bm, Cm, biasRow, biasCol, Res, K, lda, ldb, ldc, scale, sA, sB, sC, sRes

__global__ __launch_bounds__(256) void gemm_qkv(GEMM_ARGS) { gemm_body<0>(GEMM_PASS); }
__global__ __launch_bounds__(256) void gemm_pv(GEMM_ARGS)  { gemm_body<2>(GEMM_PASS); }
__global__ __launch_bounds__(256) void gemm_res(GEMM_ARGS) { gemm_body<3>(GEMM_PASS); }

// ================= S-GEMM fine-phase 256x256 engine (gemm_s8p) =================
// BK=64, 512 thr, 8 waves. Per-wave frags interleaved across tile halves:
//   m-frag mi: rows (mi>>2)*128 + (wave>>2)*64 + (mi&3)*16   (mi 0-3 in h0, 4-7 in h1)
//   n-frag ni: cols (ni>>1)*128 + (wave&3)*32 + (ni&1)*16    (ni 0-1 in h0, 2-3 in h1)
// Per K-tile: 4 phases, quadrant (mh,nh) order (0,0)(0,1)(1,1)(1,0); stage units of
// tile t+1 issued one per phase in order A0,B0,B1,A1. Hand-verified retirement:
// boundary vmcnt(4)->{A0,B0}, ph2 vmcnt(4)->B1, ph3 vmcnt(4)->A1. Never drains mid-loop.
__global__ __launch_bounds__(512)
void gemm_s8p(const unsigned short* __restrict__ A, const unsigned short* __restrict__ Bm,
              unsigned short* __restrict__ C,
              int K, int lda, int ldb, int ldc, float scale,
              long long sA, long long sB, long long sC) {
  const int nbx = gridDim.x, nby = gridDim.y;
  const int nb = nbx * nby * gridDim.z;
  int lin = (blockIdx.z * nby + blockIdx.y) * nbx + blockIdx.x;
  int bx, by, bz;
  if ((nb & 7) == 0) {
    int logical = (lin & 7) * (nb >> 3) + (lin >> 3);
    bx = logical % nbx;
    int t = logical / nbx;
    by = t % nby;
    bz = t / nby;
  } else { bx = blockIdx.x; by = blockIdx.y; bz = blockIdx.z; }

  const unsigned short* __restrict__ Ab = A + (size_t)bz * sA;
  const unsigned short* __restrict__ Bb = Bm + (size_t)bz * sB;
  unsigned short* __restrict__ Cb = C + (size_t)bz * sC;
  const int m0 = by * 256, n0 = bx * 256;

  __shared__ __align__(16) unsigned short lA[2][2][128 * 64];   // [buf][half] 64 KB
  __shared__ __align__(16) unsigned short lB[2][2][128 * 64];   // 64 KB

  const int tid = threadIdx.x, wave = tid >> 6, lane = tid & 63;
  const int wr = (wave >> 2) * 64;                  // M sub-offset within each half
  const int wcb = (wave & 3) * 32;                  // N sub-offset within each half
  const int lr = lane & 15, lkc = lane >> 4;
  f32x4 acc[8][4] = {};

  // staging address precompute (shared by A/B/half; 2 chunks per thread per unit)
  int srow[2], scol[2];
  #pragma unroll
  for (int it = 0; it < 2; ++it) {
    int chunk = it * 512 + tid;
    int row = chunk >> 3;
    srow[it] = row;
    scol[it] = ((chunk & 7) ^ (row & 7)) * 8;
  }

  // issue one stage unit: tensor T (0=A,1=B), half h, buf d, k-offset kt
  #define ISSUE(T, h, d, kt)                                                                  \
    { const unsigned short* gb = (T == 0) ? Ab : Bb;                                          \
      const int tb = ((T == 0) ? m0 : n0) + (h) * 128;                                        \
      const int ld = (T == 0) ? lda : ldb;                                                    \
      _Pragma("unroll")                                                                       \
      for (int it = 0; it < 2; ++it)                                                          \
        __builtin_amdgcn_global_load_lds(                                                     \
            (const AS1 unsigned int*)(gb + (size_t)(tb + srow[it]) * ld + (kt) + scol[it]),   \
            (AS3 unsigned int*)(((T == 0) ? &lA[d][h][0] : &lB[d][h][0]) +                    \
                                (size_t)(it * 512 + tid) * 8), 16, 0, 0);                     \
    }

  // compute quadrant (mh, nh) of current tile from buf c: 16 MFMA, 12 ds_read_b128
  #define QUAD(mh, nh, c)                                                                     \
    { _Pragma("unroll")                                                                       \
      for (int kk = 0; kk < 64; kk += 32) {                                                   \
        const int jb = (kk >> 3) + lkc;                                                       \
        s16x8 af[4], bf2[2];                                                                  \
        _Pragma("unroll")                                                                     \
        for (int mi = 0; mi < 4; ++mi) {                                                      \
          int ra = wr + mi * 16 + lr;                                                         \
          af[mi] = *(const s16x8*)&lA[c][mh][ra * 64 + ((jb ^ (ra & 7)) << 3)];               \
        }                                                                                     \
        _Pragma("unroll")                                                                     \
        for (int nj = 0; nj < 2; ++nj) {                                                      \
          int rb = wcb + nj * 16 + lr;                                                        \
          bf2[nj] = *(const s16x8*)&lB[c][nh][rb * 64 + ((jb ^ (rb & 7)) << 3)];              \
        }                                                                                     \
        __builtin_amdgcn_s_setprio(1);                                                        \
        _Pragma("unroll")                                                                     \
        for (int mi = 0; mi < 4; ++mi)                                                        \
          _Pragma("unroll")                                                                   \
          for (int nj = 0; nj < 2; ++nj)                                                      \
            acc[(mh) * 4 + mi][(nh) * 2 + nj] = __builtin_amdgcn_mfma_f32_16x16x32_bf16(      \
                af[mi], bf2[nj], acc[(mh) * 4 + mi][(nh) * 2 + nj], 0, 0, 0);                 \
        __builtin_amdgcn_s_setprio(0);                                                        \
      }                                                                                       \
    }

  #define WAITV(n)                                                                            \
    { asm volatile("s_waitcnt vmcnt(" #n ")" ::: "memory");                                   \
      __builtin_amdgcn_sched_barrier(0);                                                      \
      __builtin_amdgcn_s_barrier();                                                           \
      __builtin_amdgcn_sched_barrier(0); }

  const int nkt = K >> 6;                           // 8 for K=512 (requires >=2)
  // prologue: full tile 0 staged, one-time drain
  ISSUE(0, 0, 0, 0); ISSUE(1, 0, 0, 0); ISSUE(1, 1, 0, 0); ISSUE(0, 1, 0, 0);
  WAITV(0);

  for (int t = 0; t < nkt; ++t) {
    const int c = t & 1;
    const int kn = (t + 1) * 64;
    const bool stg = (t + 1 < nkt);
    // ph1: quadrant (0,0) [needs A0,B0 - retired at previous boundary]
    if (stg) ISSUE(0, 0, c ^ 1, kn);
    QUAD(0, 0, c);
    // ph2: quadrant (0,1) [needs B1 = 3rd-oldest outstanding unit]
    if (stg) { WAITV(4); } else { WAITV(2); }
    if (stg) ISSUE(1, 0, c ^ 1, kn);
    QUAD(0, 1, c);
    // ph3: quadrant (1,1) [needs A1 = next-oldest]
    if (stg) { WAITV(4); } else { WAITV(0); }
    if (stg) ISSUE(1, 1, c ^ 1, kn);
    QUAD(1, 1, c);
    // ph4: quadrant (1,0) [nothing new]
    if (stg) ISSUE(0, 1, c ^ 1, kn);
    QUAD(1, 0, c);
    // boundary: next tile's A0,B0 must land
    if (stg) { WAITV(4); }
  }
  #undef ISSUE
  #undef QUAD
  #undef WAITV

  // epilogue: C = exp(acc * scale), bf16
  const int r0 = (lane >> 4) * 4, ccol = lane & 15;
  #pragma unroll
  for (int mi = 0; mi < 8; ++mi) {
    const int gm = m0 + (mi >> 2) * 128 + wr + (mi & 3) * 16 + r0;
    #pragma unroll
    for (int ni = 0; ni < 4; ++ni) {
      const int gn = n0 + (ni >> 1) * 128 + wcb + (ni & 1) * 16 + ccol;
      #pragma unroll
      for (int r = 0; r < 4; ++r) {
        float val = __expf(acc[mi][ni][r] * scale);
        Cb[(size_t)(gm + r) * ldc + gn] = f2bf(val);
      }
    }
  }
}

extern "C" void kernel_launch(void* const* d_in, const int* in_sizes, int n_in,
                              void* d_out, int out_size, void* d_ws, size_t ws_size,
                              hipStream_t stream) {
  (void)in_sizes; (void)n_in; (void)out_size;
  const float* x   = (const float*)d_in[0];
  const float* nsc = (const float*)d_in[1];
  const float* nbi = (const float*)d_in[2];
  const float* wq  = (const float*)d_in[3];
  const float* bq  = (const float*)d_in[4];
  const float* wk  = (const float*)d_in[5];
  const float* bk  = (const float*)d_in[6];
  const float* wv  = (const float*)d_in[7];
  const float* bv  = (const float*)d_in[8];
  const float* wp  = (const float*)d_in[9];
  const float* bp  = (const float*)d_in[10];
  float* out = (float*)d_out;
  char* ws = (char*)d_ws;

  const size_t nW = (size_t)CCH * CCH;
  unsigned short* wb = (unsigned short*)ws;            // 2 MB
  float* bcat = (float*)(ws + 4 * nW * 2);             // 6 KB
  float* stats = bcat + 1536;                          // 2 KB
  const size_t o_h = 4 * nW * 2 + 16384;
  unsigned short* ht  = (unsigned short*)(ws + o_h);   // 32 MB  (b, p, 512)
  unsigned short* qkv = ht + (size_t)BATCH * HWP * CCH;        // 96 MB (b, p, 1536)
  unsigned short* vT  = qkv + (size_t)BATCH * HWP * 1536;      // 32 MB (b, c, p)
  unsigned short* Sb  = vT + (size_t)BATCH * CCH * HWP;        // G*32 MB slice (reused)
  unsigned short* ot  = ht;                            // alias: ht dead after QKV gemm
  const size_t o_S = o_h + ((size_t)BATCH * HWP * (CCH + 1536 + CCH)) * 2;
  const size_t sS1b = (size_t)HWP * HWP * 2;
  int G = 4;
  while (G > 1 && o_S + (size_t)G * sS1b > ws_size) G >>= 1;

  const long long sHC  = (long long)HWP * CCH;
  const long long sQKV = (long long)HWP * 1536;
  const long long sS1  = (long long)HWP * HWP;

  cvt_w<<<dim3((unsigned)((nW + 255) / 256)), dim3(256), 0, stream>>>(
      wq, wk, wv, wp, bq, bk, bv, wb, bcat);
  gn_stats<<<dim3(BATCH * NG), dim3(256), 0, stream>>>(x, stats);
  gn_apply<<<dim3(HWP / 64, CCH / 64, BATCH), dim3(256), 0, stream>>>(x, stats, nsc, nbi, ht);

  // fused QKV: qkv[p][o] = sum_c h_t[p][c] wqkv[o][c] + bcat[o];
  // V column-blocks (o>=1024) are written TRANSPOSED into vT (Res param = vT, sRes = sHC)
  gemm_qkv<<<dim3(1536 / 128, HWP / 128, BATCH), dim3(256), 0, stream>>>(
      ht, wb, qkv, nullptr, bcat, (const float*)vT,
      CCH, CCH, CCH, 1536, 1.f, sHC, 0, sQKV, sHC);

  const float sc = 0.04419417382415922f;               // 512^-0.5
  for (int b0 = 0; b0 < BATCH; b0 += G) {
    // expS[d][e] = exp(sc * sum_c q[d][c] k[e][c])   (fine-phase 256^2 engine)
    gemm_s8p<<<dim3(HWP / 256, HWP / 256, G), dim3(512), 0, stream>>>(
        qkv + (size_t)b0 * sQKV, qkv + 512 + (size_t)b0 * sQKV, Sb,
        CCH, 1536, 1536, HWP, sc, sQKV, sQKV, sS1);
    // o_t[d][c] = (sum_e expS[d][e] vT[c][e]) / (sum_e expS[d][e])   (fused denominator)
    gemm_pv<<<dim3(CCH / 128, HWP / 128, G), dim3(256), 0, stream>>>(
        Sb, vT + (size_t)b0 * sHC, ot + (size_t)b0 * sHC,
        nullptr, nullptr, nullptr,
        HWP, HWP, HWP, CCH, 1.f, sS1, sHC, sHC, 0);
  }

  // final: out[o][p] = x[o][p] + bp[o] + sum_c wp[o][c] o_t[p][c]   (f32, x prefetched)
  gemm_res<<<dim3(HWP / 128, CCH / 128, BATCH), dim3(256), 0, stream>>>(
      wb + 3 * nW, ot, out, bp, nullptr, x,
      CCH, CCH, CCH, HWP, 1.f, 0, sHC, sHC, sHC);
}

// Round 16
// 663.010 us; speedup vs baseline: 1.0820x; 1.0820x over previous
//
#include <hip/hip_runtime.h>

// AttnBlock2D: GroupNorm -> fused QKV -> 1-head attention (hw=4096, dh=512) -> proj + residual
// FINAL (R16) = R14 verbatim, the session-best configuration (660.9 / 663.0 us, reproduced).
// R15's fine-phase S engine regressed at K=512 and is reverted.
// Banked wins vs baseline (1093us): fused QKV GEMM; softmax eliminated into GEMM epilogues
// (exp in S epilogue + ones-MFMA row-denominator in PV); V-transpose fused into QKV
// epilogue; residual register-prefetch in final projection; coalesced f32 epilogue;
// bijective XCD swizzle + both-sides LDS XOR swizzle; L3-resident S slicing (G=4).

#define BATCH 8
#define CCH 512
#define HWP 4096
#define NG 32

#define AS1 __attribute__((address_space(1)))
#define AS3 __attribute__((address_space(3)))

typedef __attribute__((ext_vector_type(8))) short s16x8;
typedef __attribute__((ext_vector_type(4))) float f32x4;

__device__ __forceinline__ unsigned short f2bf(float f) {
  union { float f; unsigned u; } v; v.f = f;
  return (unsigned short)((v.u + 0x7FFFu + ((v.u >> 16) & 1u)) >> 16);
}

// ---------------- weight convert f32 -> bf16 (4 matrices) + qkv bias concat ----------------
__global__ void cvt_w(const float* __restrict__ w0, const float* __restrict__ w1,
                      const float* __restrict__ w2, const float* __restrict__ w3,
                      const float* __restrict__ bq, const float* __restrict__ bk,
                      const float* __restrict__ bv,
                      unsigned short* __restrict__ out, float* __restrict__ bcat) {
  int i = blockIdx.x * 256 + threadIdx.x;
  const int n = CCH * CCH;
  if (i < CCH) {
    bcat[i]           = bq[i];
    bcat[CCH + i]     = bk[i];
    bcat[2 * CCH + i] = bv[i];
  }
  if (i < n) {
    out[i]         = f2bf(w0[i]);
    out[n + i]     = f2bf(w1[i]);
    out[2 * n + i] = f2bf(w2[i]);
    out[3 * n + i] = f2bf(w3[i]);
  }
}

// ---------------- GroupNorm stats: one block per (b,g) ----------------
__global__ void gn_stats(const float* __restrict__ x, float* __restrict__ stats) {
  const int bg = blockIdx.x;
  const float* base = x + (size_t)bg * (16 * HWP);
  float s = 0.f, sq = 0.f;
  for (int i = threadIdx.x; i < 16 * HWP / 4; i += 256) {
    float4 v = ((const float4*)base)[i];
    s += v.x + v.y + v.z + v.w;
    sq += v.x * v.x + v.y * v.y + v.z * v.z + v.w * v.w;
  }
  #pragma unroll
  for (int o = 32; o; o >>= 1) { s += __shfl_xor(s, o); sq += __shfl_xor(sq, o); }
  __shared__ float ls[4], lq[4];
  const int wv = threadIdx.x >> 6;
  if ((threadIdx.x & 63) == 0) { ls[wv] = s; lq[wv] = sq; }
  __syncthreads();
  if (threadIdx.x == 0) {
    s = ls[0] + ls[1] + ls[2] + ls[3];
    sq = lq[0] + lq[1] + lq[2] + lq[3];
    const float inv_n = 1.f / (16.f * HWP);
    float mean = s * inv_n;
    float var = sq * inv_n - mean * mean;
    stats[2 * bg] = mean;
    stats[2 * bg + 1] = rsqrtf(var + 1e-5f);
  }
}

// ---------------- GroupNorm apply + transpose -> h_t (hw, c) bf16 ----------------
__global__ void gn_apply(const float* __restrict__ x, const float* __restrict__ stats,
                         const float* __restrict__ scale, const float* __restrict__ bias,
                         unsigned short* __restrict__ ht) {
  const int p0 = blockIdx.x * 64, c0 = blockIdx.y * 64, b = blockIdx.z;
  const int tx = threadIdx.x & 63, ty = threadIdx.x >> 6;
  __shared__ unsigned short tile[64][65];
  #pragma unroll 4
  for (int j = 0; j < 16; ++j) {
    int cl = ty + j * 4;
    int c = c0 + cl;
    int g = c >> 4;
    float mean = stats[(b * NG + g) * 2];
    float rstd = stats[(b * NG + g) * 2 + 1];
    float v = x[((size_t)(b * CCH + c)) * HWP + p0 + tx];
    v = (v - mean) * rstd * scale[c] + bias[c];
    tile[cl][tx] = f2bf(v);
  }
  __syncthreads();
  #pragma unroll 4
  for (int j = 0; j < 16; ++j) {
    int pl = ty + j * 4;
    ht[((size_t)b * HWP + p0 + pl) * CCH + c0 + tx] = tile[tx][pl];
  }
}

// ---------------- NT GEMM (R3 engine): C = scale*A[M,K]*B[N,K]^T, 128x128, BK=64, dbuf ----------------
// MODE 0: bf16 out + biasCol; if Res!=null and n0>=1024, tile is V: transpose via LDS
//         bounce (pad 152) and write to vT (=Res, stride sRes).  (fused QKV+V^T)
// MODE 2: bf16 out, v / rowsum(A)         (PV with fused softmax denominator)
// MODE 3: f32 out, + biasRow + Res(prefetched to regs), coalesced epilogue (final proj)
template<int MODE>
__device__ __forceinline__ void gemm_body(
    const unsigned short* __restrict__ A, const unsigned short* __restrict__ Bm,
    void* __restrict__ Cm, const float* __restrict__ biasRow,
    const float* __restrict__ biasCol, const float* __restrict__ Res,
    int K, int lda, int ldb, int ldc, float scale,
    long long sA, long long sB, long long sC, long long sRes) {
  // --- bijective XCD swizzle ---
  const int nbx = gridDim.x, nby = gridDim.y;
  const int nb = nbx * nby * gridDim.z;
  int lin = (blockIdx.z * nby + blockIdx.y) * nbx + blockIdx.x;
  int bx, by, bz;
  if ((nb & 7) == 0) {
    int logical = (lin & 7) * (nb >> 3) + (lin >> 3);
    bx = logical % nbx;
    int t = logical / nbx;
    by = t % nby;
    bz = t / nby;
  } else { bx = blockIdx.x; by = blockIdx.y; bz = blockIdx.z; }

  const unsigned short* Ab = A + (size_t)bz * sA;
  const unsigned short* Bb = Bm + (size_t)bz * sB;
  const int m0 = by * 128, n0 = bx * 128;
  __shared__ __align__(16) unsigned short sm[2][2][128 * 64];  // [A/B][dbuf][tile]
  const int tid = threadIdx.x, wave = tid >> 6, lane = tid & 63;
  const int wr = (wave >> 1) * 64, wc = (wave & 1) * 64;
  const int lr = lane & 15, lkc = lane >> 4;
  f32x4 acc[4][4] = {};
  f32x4 acc_d[4] = {};                               // MODE 2: row-sum
  s16x8 bones;
  #pragma unroll
  for (int j = 0; j < 8; ++j) bones[j] = (short)0x3F80;  // bf16 1.0

  // MODE 3: prefetch the residual tile into registers (read hides under the K-loop)
  float4 xr[16];
  if (MODE == 3) {
    #pragma unroll
    for (int pass = 0; pass < 2; ++pass)
      #pragma unroll
      for (int i = 0; i < 8; ++i) {
        int idx = i * 256 + tid;
        int rrow = idx >> 5, c4 = (idx & 31) << 2;
        size_t gidx = (size_t)(m0 + pass * 64 + rrow) * ldc + (n0 + c4);
        xr[pass * 8 + i] = *(const float4*)&Res[(size_t)bz * sRes + gidx];
      }
  }

  const int chunkBase = wave * 64 + lane;
  int srow[4], sc8[4];
  #pragma unroll
  for (int it = 0; it < 4; ++it) {
    int chunk = it * 256 + chunkBase;
    srow[it] = chunk >> 3;
    sc8[it] = (((chunk & 7) ^ (srow[it] & 7)) * 8);
  }

  #define STAGE(buf, kt)                                                                 \
    { _Pragma("unroll")                                                                  \
      for (int it = 0; it < 4; ++it) {                                                   \
        __builtin_amdgcn_global_load_lds(                                                \
            (const AS1 unsigned int*)(Ab + (size_t)(m0 + srow[it]) * lda + (kt) + sc8[it]), \
            (AS3 unsigned int*)(&sm[0][buf][0] + (size_t)(it * 256 + wave * 64) * 8), 16, 0, 0); \
        __builtin_amdgcn_global_load_lds(                                                \
            (const AS1 unsigned int*)(Bb + (size_t)(n0 + srow[it]) * ldb + (kt) + sc8[it]), \
            (AS3 unsigned int*)(&sm[1][buf][0] + (size_t)(it * 256 + wave * 64) * 8), 16, 0, 0); \
      }                                                                                  \
    }

  STAGE(0, 0);
  __syncthreads();
  int cur = 0;
  for (int kt = 0; kt < K; kt += 64) {
    if (kt + 64 < K) STAGE(cur ^ 1, kt + 64);
    #pragma unroll
    for (int kk = 0; kk < 64; kk += 32) {
      const int jbase = (kk >> 3) + lkc;
      s16x8 af[4], bfv[4];
      #pragma unroll
      for (int m = 0; m < 4; ++m) {
        int r = wr + m * 16 + lr;
        af[m] = *(const s16x8*)&sm[0][cur][r * 64 + ((jbase ^ (r & 7)) << 3)];
      }
      #pragma unroll
      for (int n = 0; n < 4; ++n) {
        int r = wc + n * 16 + lr;
        bfv[n] = *(const s16x8*)&sm[1][cur][r * 64 + ((jbase ^ (r & 7)) << 3)];
      }
      #pragma unroll
      for (int m = 0; m < 4; ++m) {
        #pragma unroll
        for (int n = 0; n < 4; ++n)
          acc[m][n] = __builtin_amdgcn_mfma_f32_16x16x32_bf16(af[m], bfv[n], acc[m][n], 0, 0, 0);
        if (MODE == 2)
          acc_d[m] = __builtin_amdgcn_mfma_f32_16x16x32_bf16(af[m], bones, acc_d[m], 0, 0, 0);
      }
    }
    __syncthreads();
    cur ^= 1;
  }
  #undef STAGE

  const int r0 = (lane >> 4) * 4, ccol = lane & 15;
  if (MODE == 0 && Res != nullptr && n0 >= 1024) {
    // ---- V-block: transpose tile via LDS bounce (pad 152 -> 2-way banks) -> vT (b,c,p) ----
    unsigned short* lt = (unsigned short*)&sm[0][0][0];   // [128][152] bf16 (38 KB)
    #pragma unroll
    for (int m = 0; m < 4; ++m) {
      const int gm_l = wr + m * 16 + r0;                  // local p-row (mult of 4)
      #pragma unroll
      for (int n = 0; n < 4; ++n) {
        const int gn_l = wc + n * 16 + ccol;              // local o-col
        const float bc = biasCol ? biasCol[n0 + gn_l] : 0.f;
        union { unsigned short us[4]; uint2 u2; } pk;
        #pragma unroll
        for (int r = 0; r < 4; ++r) pk.us[r] = f2bf(acc[m][n][r] + bc);
        *(uint2*)&lt[gn_l * 152 + gm_l] = pk.u2;          // transposed: [o][p]
      }
    }
    __syncthreads();
    unsigned short* vout = (unsigned short*)Res;          // vT base
    const int c0v = n0 - 1024;
    #pragma unroll
    for (int i = 0; i < 8; ++i) {
      int idx = i * 256 + tid;
      int orow = idx >> 4, pc = (idx & 15) * 8;
      s16x8 v = *(const s16x8*)&lt[orow * 152 + pc];
      *(s16x8*)&vout[(size_t)bz * sRes + (size_t)(c0v + orow) * HWP + m0 + pc] = v;
    }
  } else if (MODE != 3) {
    #pragma unroll
    for (int m = 0; m < 4; ++m) {
      const int gm = m0 + wr + m * 16 + r0;
      float inv[4] = {1.f, 1.f, 1.f, 1.f};
      if (MODE == 2) {
        inv[0] = 1.f / acc_d[m][0];
        inv[1] = 1.f / acc_d[m][1];
        inv[2] = 1.f / acc_d[m][2];
        inv[3] = 1.f / acc_d[m][3];
      }
      #pragma unroll
      for (int n = 0; n < 4; ++n) {
        const int gn = n0 + wc + n * 16 + ccol;
        const float bc = (MODE == 0 && biasCol) ? biasCol[gn] : 0.f;
        #pragma unroll
        for (int r = 0; r < 4; ++r) {
          float val = acc[m][n][r];
          if (MODE == 0) val = val * scale + bc;
          if (MODE == 2) val = val * inv[r];
          size_t idx = (size_t)(gm + r) * ldc + gn;
          ((unsigned short*)Cm)[(size_t)bz * sC + idx] = f2bf(val);
        }
      }
    }
  } else {
    // f32 out: coalesced epilogue via LDS bounce; residual already in xr registers
    float* ft = (float*)&sm[0][0][0];
    float* Cf = (float*)Cm;
    #pragma unroll
    for (int pass = 0; pass < 2; ++pass) {
      __syncthreads();
      if ((wave >> 1) == pass) {
        #pragma unroll
        for (int m = 0; m < 4; ++m) {
          const int rl0 = m * 16 + (lane >> 4) * 4;
          #pragma unroll
          for (int n = 0; n < 4; ++n) {
            const int cl = wc + n * 16 + (lane & 15);
            #pragma unroll
            for (int r = 0; r < 4; ++r) {
              float val = acc[m][n][r];
              if (biasRow) val += biasRow[m0 + pass * 64 + rl0 + r];
              ft[(rl0 + r) * 132 + cl] = val;
            }
          }
        }
      }
      __syncthreads();
      #pragma unroll
      for (int i = 0; i < 8; ++i) {
        int idx = i * 256 + tid;
        int rrow = idx >> 5, c4 = (idx & 31) << 2;
        float4 v = *(const float4*)&ft[rrow * 132 + c4];
        const float4 rv = xr[pass * 8 + i];
        v.x += rv.x; v.y += rv.y; v.z += rv.z; v.w += rv.w;
        size_t gidx = (size_t)(m0 + pass * 64 + rrow) * ldc + (n0 + c4);
        *(float4*)&Cf[(size_t)bz * sC + gidx] = v;
      }
    }
  }
}

#define GEMM_ARGS const unsigned short* A, const unsigned short* Bm, void* Cm,            \
                  const float* biasRow, const float* biasCol, const float* Res,            \
                  int K, int lda, int ldb, int ldc, float scale,                           \
                  long long sA, long long sB, long long sC, long long sRes
#define GEMM_PASS A, Bm, Cm, biasRow, biasCol, Res, K, lda, ldb, ldc, scale, sA, sB, sC, sRes

__global__ __launch_bounds__(256) void gemm_qkv(GEMM_ARGS) { gemm_body<0>(GEMM_PASS); }
__global__ __launch_bounds__(256) void gemm_pv(GEMM_ARGS)  { gemm_body<2>(GEMM_PASS); }
__global__ __launch_bounds__(256) void gemm_res(GEMM_ARGS) { gemm_body<3>(GEMM_PASS); }

// ================= S-GEMM: 256x128-tile, BK=32, dbuf, 8 waves, exp epilogue =================
// LDS = 2*(256*32 + 128*32)*2B = 48KB -> 3 blocks/CU. Staged bytes/elem 12B.
// Swizzle: 64B row stride -> f(r) = (r>>1)&3, applied at staging source AND ds_read.
__global__ __launch_bounds__(512)
void gemm_s256(const unsigned short* __restrict__ A, const unsigned short* __restrict__ Bm,
               unsigned short* __restrict__ C,
               int K, int lda, int ldb, int ldc, float scale,
               long long sA, long long sB, long long sC) {
  const int nbx = gridDim.x, nby = gridDim.y;
  const int nb = nbx * nby * gridDim.z;
  int lin = (blockIdx.z * nby + blockIdx.y) * nbx + blockIdx.x;
  int bx, by, bz;
  if ((nb & 7) == 0) {
    int logical = (lin & 7) * (nb >> 3) + (lin >> 3);
    bx = logical % nbx;
    int t = logical / nbx;
    by = t % nby;
    bz = t / nby;
  } else { bx = blockIdx.x; by = blockIdx.y; bz = blockIdx.z; }

  const unsigned short* __restrict__ Ab = A + (size_t)bz * sA;
  const unsigned short* __restrict__ Bb = Bm + (size_t)bz * sB;
  unsigned short* __restrict__ Cb = C + (size_t)bz * sC;
  const int m0 = by * 256, n0 = bx * 128;

  __shared__ __align__(16) unsigned short smA[2][256 * 32];
  __shared__ __align__(16) unsigned short smB[2][128 * 32];

  const int tid = threadIdx.x, wave = tid >> 6, lane = tid & 63;
  const int wr = (wave >> 1) * 64;
  const int wc = (wave & 1) * 64;
  const int lr = lane & 15, lkc = lane >> 4;
  f32x4 acc[4][4] = {};

  int aRow[2], aCol[2];
  #pragma unroll
  for (int it = 0; it < 2; ++it) {
    int chunk = it * 512 + tid;
    int row = chunk >> 2, cc = chunk & 3;
    aRow[it] = row;
    aCol[it] = ((cc ^ ((row >> 1) & 3)) * 8);
  }
  const int bRow = tid >> 2;
  const int bCol = (((tid & 3) ^ ((bRow >> 1) & 3)) * 8);

  #define STG_S(buf, kt)                                                                      \
    { _Pragma("unroll")                                                                       \
      for (int it = 0; it < 2; ++it)                                                          \
        __builtin_amdgcn_global_load_lds(                                                     \
            (const AS1 unsigned int*)(Ab + (size_t)(m0 + aRow[it]) * lda + (kt) + aCol[it]),  \
            (AS3 unsigned int*)(&smA[buf][0] + (size_t)(it * 512 + tid) * 8), 16, 0, 0);      \
      __builtin_amdgcn_global_load_lds(                                                       \
          (const AS1 unsigned int*)(Bb + (size_t)(n0 + bRow) * ldb + (kt) + bCol),            \
          (AS3 unsigned int*)(&smB[buf][0] + (size_t)tid * 8), 16, 0, 0);                     \
    }

  STG_S(0, 0);
  __syncthreads();
  int cur = 0;
  for (int kt = 0; kt < K; kt += 32) {
    if (kt + 32 < K) STG_S(cur ^ 1, kt + 32);
    s16x8 af[4], bfv[4];
    #pragma unroll
    for (int m = 0; m < 4; ++m) {
      int r = wr + m * 16 + lr;
      af[m] = *(const s16x8*)&smA[cur][r * 32 + ((lkc ^ ((r >> 1) & 3)) << 3)];
    }
    #pragma unroll
    for (int n = 0; n < 4; ++n) {
      int rb = wc + n * 16 + lr;
      bfv[n] = *(const s16x8*)&smB[cur][rb * 32 + ((lkc ^ ((rb >> 1) & 3)) << 3)];
    }
    #pragma unroll
    for (int m = 0; m < 4; ++m)
      #pragma unroll
      for (int n = 0; n < 4; ++n)
        acc[m][n] = __builtin_amdgcn_mfma_f32_16x16x32_bf16(af[m], bfv[n], acc[m][n], 0, 0, 0);
    __syncthreads();
    cur ^= 1;
  }
  #undef STG_S

  const int r0 = (lane >> 4) * 4, ccol = lane & 15;
  #pragma unroll
  for (int m = 0; m < 4; ++m) {
    const int gm = m0 + wr + m * 16 + r0;
    #pragma unroll
    for (int n = 0; n < 4; ++n) {
      const int gn = n0 + wc + n * 16 + ccol;
      #pragma unroll
      for (int r = 0; r < 4; ++r) {
        float val = __expf(acc[m][n][r] * scale);
        Cb[(size_t)(gm + r) * ldc + gn] = f2bf(val);
      }
    }
  }
}

extern "C" void kernel_launch(void* const* d_in, const int* in_sizes, int n_in,
                              void* d_out, int out_size, void* d_ws, size_t ws_size,
                              hipStream_t stream) {
  (void)in_sizes; (void)n_in; (void)out_size;
  const float* x   = (const float*)d_in[0];
  const float* nsc = (const float*)d_in[1];
  const float* nbi = (const float*)d_in[2];
  const float* wq  = (const float*)d_in[3];
  const float* bq  = (const float*)d_in[4];
  const float* wk  = (const float*)d_in[5];
  const float* bk  = (const float*)d_in[6];
  const float* wv  = (const float*)d_in[7];
  const float* bv  = (const float*)d_in[8];
  const float* wp  = (const float*)d_in[9];
  const float* bp  = (const float*)d_in[10];
  float* out = (float*)d_out;
  char* ws = (char*)d_ws;

  const size_t nW = (size_t)CCH * CCH;
  unsigned short* wb = (unsigned short*)ws;            // 2 MB
  float* bcat = (float*)(ws + 4 * nW * 2);             // 6 KB
  float* stats = bcat + 1536;                          // 2 KB
  const size_t o_h = 4 * nW * 2 + 16384;
  unsigned short* ht  = (unsigned short*)(ws + o_h);   // 32 MB  (b, p, 512)
  unsigned short* qkv = ht + (size_t)BATCH * HWP * CCH;        // 96 MB (b, p, 1536)
  unsigned short* vT  = qkv + (size_t)BATCH * HWP * 1536;      // 32 MB (b, c, p)
  unsigned short* Sb  = vT + (size_t)BATCH * CCH * HWP;        // G*32 MB slice (reused)
  unsigned short* ot  = ht;                            // alias: ht dead after QKV gemm
  const size_t o_S = o_h + ((size_t)BATCH * HWP * (CCH + 1536 + CCH)) * 2;
  const size_t sS1b = (size_t)HWP * HWP * 2;
  int G = 4;
  while (G > 1 && o_S + (size_t)G * sS1b > ws_size) G >>= 1;

  const long long sHC  = (long long)HWP * CCH;
  const long long sQKV = (long long)HWP * 1536;
  const long long sS1  = (long long)HWP * HWP;

  cvt_w<<<dim3((unsigned)((nW + 255) / 256)), dim3(256), 0, stream>>>(
      wq, wk, wv, wp, bq, bk, bv, wb, bcat);
  gn_stats<<<dim3(BATCH * NG), dim3(256), 0, stream>>>(x, stats);
  gn_apply<<<dim3(HWP / 64, CCH / 64, BATCH), dim3(256), 0, stream>>>(x, stats, nsc, nbi, ht);

  // fused QKV: qkv[p][o] = sum_c h_t[p][c] wqkv[o][c] + bcat[o];
  // V column-blocks (o>=1024) are written TRANSPOSED into vT (Res param = vT, sRes = sHC)
  gemm_qkv<<<dim3(1536 / 128, HWP / 128, BATCH), dim3(256), 0, stream>>>(
      ht, wb, qkv, nullptr, bcat, (const float*)vT,
      CCH, CCH, CCH, 1536, 1.f, sHC, 0, sQKV, sHC);

  const float sc = 0.04419417382415922f;               // 512^-0.5
  for (int b0 = 0; b0 < BATCH; b0 += G) {
    // expS[d][e] = exp(sc * sum_c q[d][c] k[e][c])   (fused exp; 256x128 BK=32 engine)
    gemm_s256<<<dim3(HWP / 128, HWP / 256, G), dim3(512), 0, stream>>>(
        qkv + (size_t)b0 * sQKV, qkv + 512 + (size_t)b0 * sQKV, Sb,
        CCH, 1536, 1536, HWP, sc, sQKV, sQKV, sS1);
    // o_t[d][c] = (sum_e expS[d][e] vT[c][e]) / (sum_e expS[d][e])   (fused denominator)
    gemm_pv<<<dim3(CCH / 128, HWP / 128, G), dim3(256), 0, stream>>>(
        Sb, vT + (size_t)b0 * sHC, ot + (size_t)b0 * sHC,
        nullptr, nullptr, nullptr,
        HWP, HWP, HWP, CCH, 1.f, sS1, sHC, sHC, 0);
  }

  // final: out[o][p] = x[o][p] + bp[o] + sum_c wp[o][c] o_t[p][c]   (f32, x prefetched)
  gemm_res<<<dim3(HWP / 128, CCH / 128, BATCH), dim3(256), 0, stream>>>(
      wb + 3 * nW, ot, out, bp, nullptr, x,
      CCH, CCH, CCH, HWP, 1.f, 0, sHC, sHC, sHC);
}

// Round 17
// 486.563 us; speedup vs baseline: 1.4744x; 1.3626x over previous
//
#include <hip/hip_runtime.h>
#include <hip/hip_fp8.h>

// AttnBlock2D: GroupNorm -> fused QKV -> 1-head attention (hw=4096, dh=512) -> proj + residual
// R17 = R16 (663us) with the attention core moved to fp8 e4m3 on the SAME dbuf skeletons:
//   - QKV epilogue writes Q,K as fp8 (qk8) and V as fp8-transposed (vT8)
//   - S = fp8x fp8 MFMA (16x16x32_fp8_fp8), epilogue exp -> fp8 P8 (max exp ~300 < 448 sat)
//   - PV = fp8 x fp8 with ones-MFMA denominator (fp8 1.0 = 0x38) -> bf16 ot
//   - G=8 (P8 = 128MB slice): single S and single PV dispatch
// gemm_res / gn / cvt_w unchanged. Fallback on absmax failure: revert to R16.

#define BATCH 8
#define CCH 512
#define HWP 4096
#define NG 32

#define AS1 __attribute__((address_space(1)))
#define AS3 __attribute__((address_space(3)))

typedef __attribute__((ext_vector_type(8))) short s16x8;
typedef __attribute__((ext_vector_type(4))) float f32x4;

__device__ __forceinline__ unsigned short f2bf(float f) {
  union { float f; unsigned u; } v; v.f = f;
  return (unsigned short)((v.u + 0x7FFFu + ((v.u >> 16) & 1u)) >> 16);
}
__device__ __forceinline__ unsigned char f2fp8(float f) {
  __hip_fp8_e4m3 h(f);                               // OCP e4m3, RNE+sat
  return (unsigned char)h.__x;
}

// ---------------- weight convert f32 -> bf16 (4 matrices) + qkv bias concat ----------------
__global__ void cvt_w(const float* __restrict__ w0, const float* __restrict__ w1,
                      const float* __restrict__ w2, const float* __restrict__ w3,
                      const float* __restrict__ bq, const float* __restrict__ bk,
                      const float* __restrict__ bv,
                      unsigned short* __restrict__ out, float* __restrict__ bcat) {
  int i = blockIdx.x * 256 + threadIdx.x;
  const int n = CCH * CCH;
  if (i < CCH) {
    bcat[i]           = bq[i];
    bcat[CCH + i]     = bk[i];
    bcat[2 * CCH + i] = bv[i];
  }
  if (i < n) {
    out[i]         = f2bf(w0[i]);
    out[n + i]     = f2bf(w1[i]);
    out[2 * n + i] = f2bf(w2[i]);
    out[3 * n + i] = f2bf(w3[i]);
  }
}

// ---------------- GroupNorm stats: one block per (b,g) ----------------
__global__ void gn_stats(const float* __restrict__ x, float* __restrict__ stats) {
  const int bg = blockIdx.x;
  const float* base = x + (size_t)bg * (16 * HWP);
  float s = 0.f, sq = 0.f;
  for (int i = threadIdx.x; i < 16 * HWP / 4; i += 256) {
    float4 v = ((const float4*)base)[i];
    s += v.x + v.y + v.z + v.w;
    sq += v.x * v.x + v.y * v.y + v.z * v.z + v.w * v.w;
  }
  #pragma unroll
  for (int o = 32; o; o >>= 1) { s += __shfl_xor(s, o); sq += __shfl_xor(sq, o); }
  __shared__ float ls[4], lq[4];
  const int wv = threadIdx.x >> 6;
  if ((threadIdx.x & 63) == 0) { ls[wv] = s; lq[wv] = sq; }
  __syncthreads();
  if (threadIdx.x == 0) {
    s = ls[0] + ls[1] + ls[2] + ls[3];
    sq = lq[0] + lq[1] + lq[2] + lq[3];
    const float inv_n = 1.f / (16.f * HWP);
    float mean = s * inv_n;
    float var = sq * inv_n - mean * mean;
    stats[2 * bg] = mean;
    stats[2 * bg + 1] = rsqrtf(var + 1e-5f);
  }
}

// ---------------- GroupNorm apply + transpose -> h_t (hw, c) bf16 ----------------
__global__ void gn_apply(const float* __restrict__ x, const float* __restrict__ stats,
                         const float* __restrict__ scale, const float* __restrict__ bias,
                         unsigned short* __restrict__ ht) {
  const int p0 = blockIdx.x * 64, c0 = blockIdx.y * 64, b = blockIdx.z;
  const int tx = threadIdx.x & 63, ty = threadIdx.x >> 6;
  __shared__ unsigned short tile[64][65];
  #pragma unroll 4
  for (int j = 0; j < 16; ++j) {
    int cl = ty + j * 4;
    int c = c0 + cl;
    int g = c >> 4;
    float mean = stats[(b * NG + g) * 2];
    float rstd = stats[(b * NG + g) * 2 + 1];
    float v = x[((size_t)(b * CCH + c)) * HWP + p0 + tx];
    v = (v - mean) * rstd * scale[c] + bias[c];
    tile[cl][tx] = f2bf(v);
  }
  __syncthreads();
  #pragma unroll 4
  for (int j = 0; j < 16; ++j) {
    int pl = ty + j * 4;
    ht[((size_t)b * HWP + p0 + pl) * CCH + c0 + tx] = tile[tx][pl];
  }
}

// ---------------- NT GEMM (R3 engine): 128x128, BK=64, dbuf, bf16 MFMA ----------------
// MODE 0: fp8 out. n0<1024: Q/K -> qk8 (ldc=1024B rows). n0>=1024: V -> byte-LDS-bounce
//         transpose -> vT8 (=Res, stride sRes bytes).   (fused QKV + V^T, all fp8)
// MODE 3: f32 out, + biasRow + Res(prefetched to regs), coalesced epilogue (final proj)
template<int MODE>
__device__ __forceinline__ void gemm_body(
    const unsigned short* __restrict__ A, const unsigned short* __restrict__ Bm,
    void* __restrict__ Cm, const float* __restrict__ biasRow,
    const float* __restrict__ biasCol, const float* __restrict__ Res,
    int K, int lda, int ldb, int ldc, float scale,
    long long sA, long long sB, long long sC, long long sRes) {
  // --- bijective XCD swizzle ---
  const int nbx = gridDim.x, nby = gridDim.y;
  const int nb = nbx * nby * gridDim.z;
  int lin = (blockIdx.z * nby + blockIdx.y) * nbx + blockIdx.x;
  int bx, by, bz;
  if ((nb & 7) == 0) {
    int logical = (lin & 7) * (nb >> 3) + (lin >> 3);
    bx = logical % nbx;
    int t = logical / nbx;
    by = t % nby;
    bz = t / nby;
  } else { bx = blockIdx.x; by = blockIdx.y; bz = blockIdx.z; }

  const unsigned short* Ab = A + (size_t)bz * sA;
  const unsigned short* Bb = Bm + (size_t)bz * sB;
  const int m0 = by * 128, n0 = bx * 128;
  __shared__ __align__(16) unsigned short sm[2][2][128 * 64];  // [A/B][dbuf][tile]
  const int tid = threadIdx.x, wave = tid >> 6, lane = tid & 63;
  const int wr = (wave >> 1) * 64, wc = (wave & 1) * 64;
  const int lr = lane & 15, lkc = lane >> 4;
  f32x4 acc[4][4] = {};

  // MODE 3: prefetch the residual tile into registers (read hides under the K-loop)
  float4 xr[16];
  if (MODE == 3) {
    #pragma unroll
    for (int pass = 0; pass < 2; ++pass)
      #pragma unroll
      for (int i = 0; i < 8; ++i) {
        int idx = i * 256 + tid;
        int rrow = idx >> 5, c4 = (idx & 31) << 2;
        size_t gidx = (size_t)(m0 + pass * 64 + rrow) * ldc + (n0 + c4);
        xr[pass * 8 + i] = *(const float4*)&Res[(size_t)bz * sRes + gidx];
      }
  }

  const int chunkBase = wave * 64 + lane;
  int srow[4], sc8[4];
  #pragma unroll
  for (int it = 0; it < 4; ++it) {
    int chunk = it * 256 + chunkBase;
    srow[it] = chunk >> 3;
    sc8[it] = (((chunk & 7) ^ (srow[it] & 7)) * 8);
  }

  #define STAGE(buf, kt)                                                                 \
    { _Pragma("unroll")                                                                  \
      for (int it = 0; it < 4; ++it) {                                                   \
        __builtin_amdgcn_global_load_lds(                                                \
            (const AS1 unsigned int*)(Ab + (size_t)(m0 + srow[it]) * lda + (kt) + sc8[it]), \
            (AS3 unsigned int*)(&sm[0][buf][0] + (size_t)(it * 256 + wave * 64) * 8), 16, 0, 0); \
        __builtin_amdgcn_global_load_lds(                                                \
            (const AS1 unsigned int*)(Bb + (size_t)(n0 + srow[it]) * ldb + (kt) + sc8[it]), \
            (AS3 unsigned int*)(&sm[1][buf][0] + (size_t)(it * 256 + wave * 64) * 8), 16, 0, 0); \
      }                                                                                  \
    }

  STAGE(0, 0);
  __syncthreads();
  int cur = 0;
  for (int kt = 0; kt < K; kt += 64) {
    if (kt + 64 < K) STAGE(cur ^ 1, kt + 64);
    #pragma unroll
    for (int kk = 0; kk < 64; kk += 32) {
      const int jbase = (kk >> 3) + lkc;
      s16x8 af[4], bfv[4];
      #pragma unroll
      for (int m = 0; m < 4; ++m) {
        int r = wr + m * 16 + lr;
        af[m] = *(const s16x8*)&sm[0][cur][r * 64 + ((jbase ^ (r & 7)) << 3)];
      }
      #pragma unroll
      for (int n = 0; n < 4; ++n) {
        int r = wc + n * 16 + lr;
        bfv[n] = *(const s16x8*)&sm[1][cur][r * 64 + ((jbase ^ (r & 7)) << 3)];
      }
      #pragma unroll
      for (int m = 0; m < 4; ++m)
        #pragma unroll
        for (int n = 0; n < 4; ++n)
          acc[m][n] = __builtin_amdgcn_mfma_f32_16x16x32_bf16(af[m], bfv[n], acc[m][n], 0, 0, 0);
    }
    __syncthreads();
    cur ^= 1;
  }
  #undef STAGE

  const int r0 = (lane >> 4) * 4, ccol = lane & 15;
  if (MODE == 0) {
    if (n0 >= 1024) {
      // ---- V-block: fp8 transpose via byte LDS bounce [128][136] -> vT8 (b,c,p) ----
      unsigned char* ltb = (unsigned char*)&sm[0][0][0];  // 17408 B
      #pragma unroll
      for (int m = 0; m < 4; ++m) {
        const int gm_l = wr + m * 16 + r0;                // local p-row (mult of 4)
        #pragma unroll
        for (int n = 0; n < 4; ++n) {
          const int gn_l = wc + n * 16 + ccol;            // local o-col
          const float bc = biasCol ? biasCol[n0 + gn_l] : 0.f;
          union { unsigned char b[4]; unsigned u; } pk;
          #pragma unroll
          for (int r = 0; r < 4; ++r) pk.b[r] = f2fp8(acc[m][n][r] * scale + bc);
          *(unsigned*)&ltb[gn_l * 136 + gm_l] = pk.u;     // transposed: [o][p]
        }
      }
      __syncthreads();
      unsigned char* vout = (unsigned char*)Res;          // vT8 base
      const int c0v = n0 - 1024;
      #pragma unroll
      for (int i = 0; i < 8; ++i) {
        int idx = i * 256 + tid;
        int orow = idx >> 4, pc = (idx & 15) * 8;
        unsigned long long v8 = *(const unsigned long long*)&ltb[orow * 136 + pc];
        *(unsigned long long*)&vout[(size_t)bz * sRes + (size_t)(c0v + orow) * HWP + m0 + pc] = v8;
      }
    } else {
      // ---- Q/K block: fp8 out to qk8 (ldc bytes per p-row) ----
      unsigned char* C8 = (unsigned char*)Cm;
      #pragma unroll
      for (int m = 0; m < 4; ++m) {
        const int gm = m0 + wr + m * 16 + r0;
        #pragma unroll
        for (int n = 0; n < 4; ++n) {
          const int gn = n0 + wc + n * 16 + ccol;
          const float bc = biasCol ? biasCol[gn] : 0.f;
          #pragma unroll
          for (int r = 0; r < 4; ++r) {
            float val = acc[m][n][r] * scale + bc;
            C8[(size_t)bz * sC + (size_t)(gm + r) * ldc + gn] = f2fp8(val);
          }
        }
      }
    }
  } else {
    // f32 out: coalesced epilogue via LDS bounce; residual already in xr registers
    float* ft = (float*)&sm[0][0][0];
    float* Cf = (float*)Cm;
    #pragma unroll
    for (int pass = 0; pass < 2; ++pass) {
      __syncthreads();
      if ((wave >> 1) == pass) {
        #pragma unroll
        for (int m = 0; m < 4; ++m) {
          const int rl0 = m * 16 + (lane >> 4) * 4;
          #pragma unroll
          for (int n = 0; n < 4; ++n) {
            const int cl = wc + n * 16 + (lane & 15);
            #pragma unroll
            for (int r = 0; r < 4; ++r) {
              float val = acc[m][n][r];
              if (biasRow) val += biasRow[m0 + pass * 64 + rl0 + r];
              ft[(rl0 + r) * 132 + cl] = val;
            }
          }
        }
      }
      __syncthreads();
      #pragma unroll
      for (int i = 0; i < 8; ++i) {
        int idx = i * 256 + tid;
        int rrow = idx >> 5, c4 = (idx & 31) << 2;
        float4 v = *(const float4*)&ft[rrow * 132 + c4];
        const float4 rv = xr[pass * 8 + i];
        v.x += rv.x; v.y += rv.y; v.z += rv.z; v.w += rv.w;
        size_t gidx = (size_t)(m0 + pass * 64 + rrow) * ldc + (n0 + c4);
        *(float4*)&Cf[(size_t)bz * sC + gidx] = v;
      }
    }
  }
}

#define GEMM_ARGS const unsigned short* A, const unsigned short* Bm, void* Cm,            \
                  const float* biasRow, const float* biasCol, const float* Res,            \
                  int K, int lda, int ldb, int ldc, float scale,                           \
                  long long sA, long long sB, long long sC, long long sRes
#define GEMM_PASS A, Bm, Cm, biasRow, biasCol, Res, K, lda, ldb, ldc, scale, sA, sB, sC, sRes

__global__ __launch_bounds__(256) void gemm_qkv(GEMM_ARGS) { gemm_body<0>(GEMM_PASS); }
__global__ __launch_bounds__(256) void gemm_res(GEMM_ARGS) { gemm_body<3>(GEMM_PASS); }

// ================= S-GEMM fp8: 256x128-tile, BK=64, dbuf, 8 waves, exp->fp8 epilogue =================
// A=q8, B=k8 (1024B rows), fp8x fp8 MFMA (8 fp8/lane, k=(lane>>4)*8+j — same map as bf16).
// LDS = 2*(256*64 + 128*64) = 48KB -> 3 blocks/CU. Swizzle (64B rows, 16B chunks):
// f(r)=(r>>1)&3 both-sides (2-way/free: rows r and r+8 alias).
__global__ __launch_bounds__(512)
void gemm_s8(const unsigned char* __restrict__ A, const unsigned char* __restrict__ Bm,
             unsigned char* __restrict__ C,
             int K, int lda, int ldb, int ldc, float scale,
             long long sA, long long sB, long long sC) {
  const int nbx = gridDim.x, nby = gridDim.y;
  const int nb = nbx * nby * gridDim.z;
  int lin = (blockIdx.z * nby + blockIdx.y) * nbx + blockIdx.x;
  int bx, by, bz;
  if ((nb & 7) == 0) {
    int logical = (lin & 7) * (nb >> 3) + (lin >> 3);
    bx = logical % nbx;
    int t = logical / nbx;
    by = t % nby;
    bz = t / nby;
  } else { bx = blockIdx.x; by = blockIdx.y; bz = blockIdx.z; }

  const unsigned char* __restrict__ Ab = A + (size_t)bz * sA;
  const unsigned char* __restrict__ Bb = Bm + (size_t)bz * sB;
  unsigned char* __restrict__ Cb = C + (size_t)bz * sC;
  const int m0 = by * 256, n0 = bx * 128;

  __shared__ __align__(16) unsigned char smA[2][256 * 64];   // 32 KB
  __shared__ __align__(16) unsigned char smB[2][128 * 64];   // 16 KB

  const int tid = threadIdx.x, wave = tid >> 6, lane = tid & 63;
  const int wr = (wave >> 1) * 64;                  // 4 M-groups of 64
  const int wc = (wave & 1) * 64;                   // 2 N-groups of 64
  const int lr = lane & 15, lkc = lane >> 4;
  f32x4 acc[4][4] = {};

  // staging: A 16KB = 1024 16B-chunks -> 2/thread; B 512 chunks -> 1/thread
  int aRow[2], aCol[2];
  #pragma unroll
  for (int it = 0; it < 2; ++it) {
    int chunk = it * 512 + tid;
    int row = chunk >> 2, cc = chunk & 3;
    aRow[it] = row;
    aCol[it] = ((cc ^ ((row >> 1) & 3)) << 4);
  }
  const int bRow = tid >> 2;
  const int bCol = (((tid & 3) ^ ((bRow >> 1) & 3)) << 4);

  #define STG8(buf, kt)                                                                       \
    { _Pragma("unroll")                                                                       \
      for (int it = 0; it < 2; ++it)                                                          \
        __builtin_amdgcn_global_load_lds(                                                     \
            (const AS1 unsigned int*)(Ab + (size_t)(m0 + aRow[it]) * lda + (kt) + aCol[it]),  \
            (AS3 unsigned int*)(&smA[buf][0] + (size_t)(it * 512 + tid) * 16), 16, 0, 0);     \
      __builtin_amdgcn_global_load_lds(                                                       \
          (const AS1 unsigned int*)(Bb + (size_t)(n0 + bRow) * ldb + (kt) + bCol),            \
          (AS3 unsigned int*)(&smB[buf][0] + (size_t)tid * 16), 16, 0, 0);                    \
    }

  STG8(0, 0);
  __syncthreads();
  int cur = 0;
  for (int kt = 0; kt < K; kt += 64) {
    if (kt + 64 < K) STG8(cur ^ 1, kt + 64);
    #pragma unroll
    for (int s = 0; s < 2; ++s) {
      const int o = s * 32 + lkc * 8;
      long af[4], bfv[4];
      #pragma unroll
      for (int m = 0; m < 4; ++m) {
        int r = wr + m * 16 + lr;
        af[m] = *(const long*)&smA[cur][r * 64 + ((((o >> 4) ^ ((r >> 1) & 3)) << 4) | (o & 15))];
      }
      #pragma unroll
      for (int n = 0; n < 4; ++n) {
        int rb = wc + n * 16 + lr;
        bfv[n] = *(const long*)&smB[cur][rb * 64 + ((((o >> 4) ^ ((rb >> 1) & 3)) << 4) | (o & 15))];
      }
      #pragma unroll
      for (int m = 0; m < 4; ++m)
        #pragma unroll
        for (int n = 0; n < 4; ++n)
          acc[m][n] = __builtin_amdgcn_mfma_f32_16x16x32_fp8_fp8(af[m], bfv[n], acc[m][n], 0, 0, 0);
    }
    __syncthreads();
    cur ^= 1;
  }
  #undef STG8

  const int r0 = (lane >> 4) * 4, ccol = lane & 15;
  #pragma unroll
  for (int m = 0; m < 4; ++m) {
    const int gm = m0 + wr + m * 16 + r0;
    #pragma unroll
    for (int n = 0; n < 4; ++n) {
      const int gn = n0 + wc + n * 16 + ccol;
      #pragma unroll
      for (int r = 0; r < 4; ++r) {
        float val = __expf(acc[m][n][r] * scale);
        Cb[(size_t)(gm + r) * ldc + gn] = f2fp8(val);
      }
    }
  }
}

// ================= PV fp8: 128x128-tile, BK=64, dbuf, 4 waves, fused denominator =================
// A=P8 (4096B rows), B=vT8 (4096B rows). acc += P.V^T; acc_d += P.1 (fp8 1.0 = 0x38).
// LDS = 2*(128*64)*2 = 32KB -> 4 blocks/CU.
__global__ __launch_bounds__(256)
void gemm_pv8(const unsigned char* __restrict__ A, const unsigned char* __restrict__ Bm,
              unsigned short* __restrict__ C,
              int K, int lda, int ldb, int ldc,
              long long sA, long long sB, long long sC) {
  const int nbx = gridDim.x, nby = gridDim.y;
  const int nb = nbx * nby * gridDim.z;
  int lin = (blockIdx.z * nby + blockIdx.y) * nbx + blockIdx.x;
  int bx, by, bz;
  if ((nb & 7) == 0) {
    int logical = (lin & 7) * (nb >> 3) + (lin >> 3);
    bx = logical % nbx;
    int t = logical / nbx;
    by = t % nby;
    bz = t / nby;
  } else { bx = blockIdx.x; by = blockIdx.y; bz = blockIdx.z; }

  const unsigned char* __restrict__ Ab = A + (size_t)bz * sA;
  const unsigned char* __restrict__ Bb = Bm + (size_t)bz * sB;
  unsigned short* __restrict__ Cb = C + (size_t)bz * sC;
  const int m0 = by * 128, n0 = bx * 128;

  __shared__ __align__(16) unsigned char pA[2][128 * 64];
  __shared__ __align__(16) unsigned char pB[2][128 * 64];

  const int tid = threadIdx.x, wave = tid >> 6, lane = tid & 63;
  const int wr = (wave >> 1) * 64, wc = (wave & 1) * 64;
  const int lr = lane & 15, lkc = lane >> 4;
  f32x4 acc[4][4] = {};
  f32x4 acc_d[4] = {};
  const long ones8 = 0x3838383838383838LL;           // 8x fp8 e4m3 1.0

  // staging: 8KB = 512 16B-chunks per tensor -> 2/thread each
  int sRow[2], sCol[2];
  #pragma unroll
  for (int it = 0; it < 2; ++it) {
    int chunk = it * 256 + tid;
    int row = chunk >> 2, cc = chunk & 3;
    sRow[it] = row;
    sCol[it] = ((cc ^ ((row >> 1) & 3)) << 4);
  }

  #define STGP(buf, kt)                                                                       \
    { _Pragma("unroll")                                                                       \
      for (int it = 0; it < 2; ++it) {                                                        \
        __builtin_amdgcn_global_load_lds(                                                     \
            (const AS1 unsigned int*)(Ab + (size_t)(m0 + sRow[it]) * lda + (kt) + sCol[it]),  \
            (AS3 unsigned int*)(&pA[buf][0] + (size_t)(it * 256 + tid) * 16), 16, 0, 0);      \
        __builtin_amdgcn_global_load_lds(                                                     \
            (const AS1 unsigned int*)(Bb + (size_t)(n0 + sRow[it]) * ldb + (kt) + sCol[it]),  \
            (AS3 unsigned int*)(&pB[buf][0] + (size_t)(it * 256 + tid) * 16), 16, 0, 0);      \
      }                                                                                       \
    }

  STGP(0, 0);
  __syncthreads();
  int cur = 0;
  for (int kt = 0; kt < K; kt += 64) {
    if (kt + 64 < K) STGP(cur ^ 1, kt + 64);
    #pragma unroll
    for (int s = 0; s < 2; ++s) {
      const int o = s * 32 + lkc * 8;
      long af[4], bfv[4];
      #pragma unroll
      for (int m = 0; m < 4; ++m) {
        int r = wr + m * 16 + lr;
        af[m] = *(const long*)&pA[cur][r * 64 + ((((o >> 4) ^ ((r >> 1) & 3)) << 4) | (o & 15))];
      }
      #pragma unroll
      for (int n = 0; n < 4; ++n) {
        int rb = wc + n * 16 + lr;
        bfv[n] = *(const long*)&pB[cur][rb * 64 + ((((o >> 4) ^ ((rb >> 1) & 3)) << 4) | (o & 15))];
      }
      #pragma unroll
      for (int m = 0; m < 4; ++m) {
        #pragma unroll
        for (int n = 0; n < 4; ++n)
          acc[m][n] = __builtin_amdgcn_mfma_f32_16x16x32_fp8_fp8(af[m], bfv[n], acc[m][n], 0, 0, 0);
        acc_d[m] = __builtin_amdgcn_mfma_f32_16x16x32_fp8_fp8(af[m], ones8, acc_d[m], 0, 0, 0);
      }
    }
    __syncthreads();
    cur ^= 1;
  }
  #undef STGP

  const int r0 = (lane >> 4) * 4, ccol = lane & 15;
  #pragma unroll
  for (int m = 0; m < 4; ++m) {
    const int gm = m0 + wr + m * 16 + r0;
    const float inv0 = 1.f / acc_d[m][0];
    const float inv1 = 1.f / acc_d[m][1];
    const float inv2 = 1.f / acc_d[m][2];
    const float inv3 = 1.f / acc_d[m][3];
    #pragma unroll
    for (int n = 0; n < 4; ++n) {
      const int gn = n0 + wc + n * 16 + ccol;
      #pragma unroll
      for (int r = 0; r < 4; ++r) {
        float val = acc[m][n][r] * (r == 0 ? inv0 : r == 1 ? inv1 : r == 2 ? inv2 : inv3);
        Cb[(size_t)(gm + r) * ldc + gn] = f2bf(val);
      }
    }
  }
}

extern "C" void kernel_launch(void* const* d_in, const int* in_sizes, int n_in,
                              void* d_out, int out_size, void* d_ws, size_t ws_size,
                              hipStream_t stream) {
  (void)in_sizes; (void)n_in; (void)out_size;
  const float* x   = (const float*)d_in[0];
  const float* nsc = (const float*)d_in[1];
  const float* nbi = (const float*)d_in[2];
  const float* wq  = (const float*)d_in[3];
  const float* bq  = (const float*)d_in[4];
  const float* wk  = (const float*)d_in[5];
  const float* bk  = (const float*)d_in[6];
  const float* wv  = (const float*)d_in[7];
  const float* bv  = (const float*)d_in[8];
  const float* wp  = (const float*)d_in[9];
  const float* bp  = (const float*)d_in[10];
  float* out = (float*)d_out;
  char* ws = (char*)d_ws;

  const size_t nW = (size_t)CCH * CCH;
  unsigned short* wb = (unsigned short*)ws;            // 2 MB (bf16 weights)
  float* bcat = (float*)(ws + 4 * nW * 2);             // 6 KB
  float* stats = bcat + 1536;                          // 2 KB
  const size_t o_h = 4 * nW * 2 + 16384;
  unsigned short* ht = (unsigned short*)(ws + o_h);    // 32 MB (b, p, 512) bf16
  unsigned char* qk8 = (unsigned char*)(ht + (size_t)BATCH * HWP * CCH);   // 32 MB (b,p,1024) fp8
  unsigned char* vT8 = qk8 + (size_t)BATCH * HWP * 1024;                   // 16 MB (b,c,p) fp8
  unsigned char* P8  = vT8 + (size_t)BATCH * CCH * HWP;                    // G*16 MB (slice)
  unsigned short* ot = ht;                             // alias: ht dead after QKV gemm
  const size_t o_P8 = o_h + (size_t)BATCH * HWP * CCH * 2
                    + (size_t)BATCH * HWP * 1024 + (size_t)BATCH * CCH * HWP;
  int G = 8;
  while (G > 1 && o_P8 + (size_t)G * HWP * HWP > ws_size) G >>= 1;

  const long long sHC  = (long long)HWP * CCH;         // bf16 elements / batch
  const long long sQK8 = (long long)HWP * 1024;        // bytes / batch
  const long long sV8  = (long long)CCH * HWP;         // bytes / batch
  const long long sP8  = (long long)HWP * HWP;         // bytes / batch

  cvt_w<<<dim3((unsigned)((nW + 255) / 256)), dim3(256), 0, stream>>>(
      wq, wk, wv, wp, bq, bk, bv, wb, bcat);
  gn_stats<<<dim3(BATCH * NG), dim3(256), 0, stream>>>(x, stats);
  gn_apply<<<dim3(HWP / 64, CCH / 64, BATCH), dim3(256), 0, stream>>>(x, stats, nsc, nbi, ht);

  // fused QKV (fp8 out): Q,K -> qk8 (b,p,1024); V -> vT8 transposed (b,c,p)
  gemm_qkv<<<dim3(1536 / 128, HWP / 128, BATCH), dim3(256), 0, stream>>>(
      ht, wb, qk8, nullptr, bcat, (const float*)vT8,
      CCH, CCH, CCH, 1024, 1.f, sHC, 0, sQK8, sV8);

  const float sc = 0.04419417382415922f;               // 512^-0.5
  for (int b0 = 0; b0 < BATCH; b0 += G) {
    // P8[d][e] = fp8(exp(sc * q8[d].k8[e]))
    gemm_s8<<<dim3(HWP / 128, HWP / 256, G), dim3(512), 0, stream>>>(
        qk8 + (size_t)b0 * sQK8, qk8 + 512 + (size_t)b0 * sQK8, P8,
        CCH, 1024, 1024, HWP, sc, sQK8, sQK8, sP8);
    // ot[d][c] = (P8[d].vT8[c]) / (P8[d].1)
    gemm_pv8<<<dim3(CCH / 128, HWP / 128, G), dim3(256), 0, stream>>>(
        P8, vT8 + (size_t)b0 * sV8, ot + (size_t)b0 * sHC,
        HWP, HWP, HWP, CCH, sP8, sV8, sHC);
  }

  // final: out[o][p] = x[o][p] + bp[o] + sum_c wp[o][c] ot[p][c]   (bf16 engine, f32 out)
  gemm_res<<<dim3(HWP / 128, CCH / 128, BATCH), dim3(256), 0, stream>>>(
      wb + 3 * nW, ot, out, bp, nullptr, x,
      CCH, CCH, CCH, HWP, 1.f, 0, sHC, sHC, sHC);
}

// Round 18
// 484.083 us; speedup vs baseline: 1.4819x; 1.0051x over previous
//
#include <hip/hip_runtime.h>
#include <hip/hip_fp8.h>

// AttnBlock2D: GroupNorm -> fused QKV -> 1-head attention (hw=4096, dh=512) -> proj + residual
// R18 = R17 (486.6us) + corrected fp8 LDS swizzle: f(r) = (r ^ (r>>2)) & 3 (both staging
//       source and ds_read) in gemm_s8 and gemm_pv8. Old f(r)=(r>>1)&3 left rows r,r+4
//       colliding -> 4-way bank conflicts (16.8M counted on pv8). New f is injective on
//       4*(r&1)+(c^f) over 8 consecutive rows -> free 2-way. Everything else unchanged.

#define BATCH 8
#define CCH 512
#define HWP 4096
#define NG 32

#define AS1 __attribute__((address_space(1)))
#define AS3 __attribute__((address_space(3)))

typedef __attribute__((ext_vector_type(8))) short s16x8;
typedef __attribute__((ext_vector_type(4))) float f32x4;

__device__ __forceinline__ unsigned short f2bf(float f) {
  union { float f; unsigned u; } v; v.f = f;
  return (unsigned short)((v.u + 0x7FFFu + ((v.u >> 16) & 1u)) >> 16);
}
__device__ __forceinline__ unsigned char f2fp8(float f) {
  __hip_fp8_e4m3 h(f);                               // OCP e4m3, RNE+sat
  return (unsigned char)h.__x;
}
__device__ __forceinline__ int swz8(int r) {         // fp8 chunk swizzle (2-way free)
  return (r ^ (r >> 2)) & 3;
}

// ---------------- weight convert f32 -> bf16 (4 matrices) + qkv bias concat ----------------
__global__ void cvt_w(const float* __restrict__ w0, const float* __restrict__ w1,
                      const float* __restrict__ w2, const float* __restrict__ w3,
                      const float* __restrict__ bq, const float* __restrict__ bk,
                      const float* __restrict__ bv,
                      unsigned short* __restrict__ out, float* __restrict__ bcat) {
  int i = blockIdx.x * 256 + threadIdx.x;
  const int n = CCH * CCH;
  if (i < CCH) {
    bcat[i]           = bq[i];
    bcat[CCH + i]     = bk[i];
    bcat[2 * CCH + i] = bv[i];
  }
  if (i < n) {
    out[i]         = f2bf(w0[i]);
    out[n + i]     = f2bf(w1[i]);
    out[2 * n + i] = f2bf(w2[i]);
    out[3 * n + i] = f2bf(w3[i]);
  }
}

// ---------------- GroupNorm stats: one block per (b,g) ----------------
__global__ void gn_stats(const float* __restrict__ x, float* __restrict__ stats) {
  const int bg = blockIdx.x;
  const float* base = x + (size_t)bg * (16 * HWP);
  float s = 0.f, sq = 0.f;
  for (int i = threadIdx.x; i < 16 * HWP / 4; i += 256) {
    float4 v = ((const float4*)base)[i];
    s += v.x + v.y + v.z + v.w;
    sq += v.x * v.x + v.y * v.y + v.z * v.z + v.w * v.w;
  }
  #pragma unroll
  for (int o = 32; o; o >>= 1) { s += __shfl_xor(s, o); sq += __shfl_xor(sq, o); }
  __shared__ float ls[4], lq[4];
  const int wv = threadIdx.x >> 6;
  if ((threadIdx.x & 63) == 0) { ls[wv] = s; lq[wv] = sq; }
  __syncthreads();
  if (threadIdx.x == 0) {
    s = ls[0] + ls[1] + ls[2] + ls[3];
    sq = lq[0] + lq[1] + lq[2] + lq[3];
    const float inv_n = 1.f / (16.f * HWP);
    float mean = s * inv_n;
    float var = sq * inv_n - mean * mean;
    stats[2 * bg] = mean;
    stats[2 * bg + 1] = rsqrtf(var + 1e-5f);
  }
}

// ---------------- GroupNorm apply + transpose -> h_t (hw, c) bf16 ----------------
__global__ void gn_apply(const float* __restrict__ x, const float* __restrict__ stats,
                         const float* __restrict__ scale, const float* __restrict__ bias,
                         unsigned short* __restrict__ ht) {
  const int p0 = blockIdx.x * 64, c0 = blockIdx.y * 64, b = blockIdx.z;
  const int tx = threadIdx.x & 63, ty = threadIdx.x >> 6;
  __shared__ unsigned short tile[64][65];
  #pragma unroll 4
  for (int j = 0; j < 16; ++j) {
    int cl = ty + j * 4;
    int c = c0 + cl;
    int g = c >> 4;
    float mean = stats[(b * NG + g) * 2];
    float rstd = stats[(b * NG + g) * 2 + 1];
    float v = x[((size_t)(b * CCH + c)) * HWP + p0 + tx];
    v = (v - mean) * rstd * scale[c] + bias[c];
    tile[cl][tx] = f2bf(v);
  }
  __syncthreads();
  #pragma unroll 4
  for (int j = 0; j < 16; ++j) {
    int pl = ty + j * 4;
    ht[((size_t)b * HWP + p0 + pl) * CCH + c0 + tx] = tile[tx][pl];
  }
}

// ---------------- NT GEMM (R3 engine): 128x128, BK=64, dbuf, bf16 MFMA ----------------
// MODE 0: fp8 out. n0<1024: Q/K -> qk8 (ldc=1024B rows). n0>=1024: V -> byte-LDS-bounce
//         transpose -> vT8 (=Res, stride sRes bytes).   (fused QKV + V^T, all fp8)
// MODE 3: f32 out, + biasRow + Res(prefetched to regs), coalesced epilogue (final proj)
template<int MODE>
__device__ __forceinline__ void gemm_body(
    const unsigned short* __restrict__ A, const unsigned short* __restrict__ Bm,
    void* __restrict__ Cm, const float* __restrict__ biasRow,
    const float* __restrict__ biasCol, const float* __restrict__ Res,
    int K, int lda, int ldb, int ldc, float scale,
    long long sA, long long sB, long long sC, long long sRes) {
  // --- bijective XCD swizzle ---
  const int nbx = gridDim.x, nby = gridDim.y;
  const int nb = nbx * nby * gridDim.z;
  int lin = (blockIdx.z * nby + blockIdx.y) * nbx + blockIdx.x;
  int bx, by, bz;
  if ((nb & 7) == 0) {
    int logical = (lin & 7) * (nb >> 3) + (lin >> 3);
    bx = logical % nbx;
    int t = logical / nbx;
    by = t % nby;
    bz = t / nby;
  } else { bx = blockIdx.x; by = blockIdx.y; bz = blockIdx.z; }

  const unsigned short* Ab = A + (size_t)bz * sA;
  const unsigned short* Bb = Bm + (size_t)bz * sB;
  const int m0 = by * 128, n0 = bx * 128;
  __shared__ __align__(16) unsigned short sm[2][2][128 * 64];  // [A/B][dbuf][tile]
  const int tid = threadIdx.x, wave = tid >> 6, lane = tid & 63;
  const int wr = (wave >> 1) * 64, wc = (wave & 1) * 64;
  const int lr = lane & 15, lkc = lane >> 4;
  f32x4 acc[4][4] = {};

  // MODE 3: prefetch the residual tile into registers (read hides under the K-loop)
  float4 xr[16];
  if (MODE == 3) {
    #pragma unroll
    for (int pass = 0; pass < 2; ++pass)
      #pragma unroll
      for (int i = 0; i < 8; ++i) {
        int idx = i * 256 + tid;
        int rrow = idx >> 5, c4 = (idx & 31) << 2;
        size_t gidx = (size_t)(m0 + pass * 64 + rrow) * ldc + (n0 + c4);
        xr[pass * 8 + i] = *(const float4*)&Res[(size_t)bz * sRes + gidx];
      }
  }

  const int chunkBase = wave * 64 + lane;
  int srow[4], sc8[4];
  #pragma unroll
  for (int it = 0; it < 4; ++it) {
    int chunk = it * 256 + chunkBase;
    srow[it] = chunk >> 3;
    sc8[it] = (((chunk & 7) ^ (srow[it] & 7)) * 8);
  }

  #define STAGE(buf, kt)                                                                 \
    { _Pragma("unroll")                                                                  \
      for (int it = 0; it < 4; ++it) {                                                   \
        __builtin_amdgcn_global_load_lds(                                                \
            (const AS1 unsigned int*)(Ab + (size_t)(m0 + srow[it]) * lda + (kt) + sc8[it]), \
            (AS3 unsigned int*)(&sm[0][buf][0] + (size_t)(it * 256 + wave * 64) * 8), 16, 0, 0); \
        __builtin_amdgcn_global_load_lds(                                                \
            (const AS1 unsigned int*)(Bb + (size_t)(n0 + srow[it]) * ldb + (kt) + sc8[it]), \
            (AS3 unsigned int*)(&sm[1][buf][0] + (size_t)(it * 256 + wave * 64) * 8), 16, 0, 0); \
      }                                                                                  \
    }

  STAGE(0, 0);
  __syncthreads();
  int cur = 0;
  for (int kt = 0; kt < K; kt += 64) {
    if (kt + 64 < K) STAGE(cur ^ 1, kt + 64);
    #pragma unroll
    for (int kk = 0; kk < 64; kk += 32) {
      const int jbase = (kk >> 3) + lkc;
      s16x8 af[4], bfv[4];
      #pragma unroll
      for (int m = 0; m < 4; ++m) {
        int r = wr + m * 16 + lr;
        af[m] = *(const s16x8*)&sm[0][cur][r * 64 + ((jbase ^ (r & 7)) << 3)];
      }
      #pragma unroll
      for (int n = 0; n < 4; ++n) {
        int r = wc + n * 16 + lr;
        bfv[n] = *(const s16x8*)&sm[1][cur][r * 64 + ((jbase ^ (r & 7)) << 3)];
      }
      #pragma unroll
      for (int m = 0; m < 4; ++m)
        #pragma unroll
        for (int n = 0; n < 4; ++n)
          acc[m][n] = __builtin_amdgcn_mfma_f32_16x16x32_bf16(af[m], bfv[n], acc[m][n], 0, 0, 0);
    }
    __syncthreads();
    cur ^= 1;
  }
  #undef STAGE

  const int r0 = (lane >> 4) * 4, ccol = lane & 15;
  if (MODE == 0) {
    if (n0 >= 1024) {
      // ---- V-block: fp8 transpose via byte LDS bounce [128][136] -> vT8 (b,c,p) ----
      unsigned char* ltb = (unsigned char*)&sm[0][0][0];  // 17408 B
      #pragma unroll
      for (int m = 0; m < 4; ++m) {
        const int gm_l = wr + m * 16 + r0;                // local p-row (mult of 4)
        #pragma unroll
        for (int n = 0; n < 4; ++n) {
          const int gn_l = wc + n * 16 + ccol;            // local o-col
          const float bc = biasCol ? biasCol[n0 + gn_l] : 0.f;
          union { unsigned char b[4]; unsigned u; } pk;
          #pragma unroll
          for (int r = 0; r < 4; ++r) pk.b[r] = f2fp8(acc[m][n][r] * scale + bc);
          *(unsigned*)&ltb[gn_l * 136 + gm_l] = pk.u;     // transposed: [o][p]
        }
      }
      __syncthreads();
      unsigned char* vout = (unsigned char*)Res;          // vT8 base
      const int c0v = n0 - 1024;
      #pragma unroll
      for (int i = 0; i < 8; ++i) {
        int idx = i * 256 + tid;
        int orow = idx >> 4, pc = (idx & 15) * 8;
        unsigned long long v8 = *(const unsigned long long*)&ltb[orow * 136 + pc];
        *(unsigned long long*)&vout[(size_t)bz * sRes + (size_t)(c0v + orow) * HWP + m0 + pc] = v8;
      }
    } else {
      // ---- Q/K block: fp8 out to qk8 (ldc bytes per p-row) ----
      unsigned char* C8 = (unsigned char*)Cm;
      #pragma unroll
      for (int m = 0; m < 4; ++m) {
        const int gm = m0 + wr + m * 16 + r0;
        #pragma unroll
        for (int n = 0; n < 4; ++n) {
          const int gn = n0 + wc + n * 16 + ccol;
          const float bc = biasCol ? biasCol[gn] : 0.f;
          #pragma unroll
          for (int r = 0; r < 4; ++r) {
            float val = acc[m][n][r] * scale + bc;
            C8[(size_t)bz * sC + (size_t)(gm + r) * ldc + gn] = f2fp8(val);
          }
        }
      }
    }
  } else {
    // f32 out: coalesced epilogue via LDS bounce; residual already in xr registers
    float* ft = (float*)&sm[0][0][0];
    float* Cf = (float*)Cm;
    #pragma unroll
    for (int pass = 0; pass < 2; ++pass) {
      __syncthreads();
      if ((wave >> 1) == pass) {
        #pragma unroll
        for (int m = 0; m < 4; ++m) {
          const int rl0 = m * 16 + (lane >> 4) * 4;
          #pragma unroll
          for (int n = 0; n < 4; ++n) {
            const int cl = wc + n * 16 + (lane & 15);
            #pragma unroll
            for (int r = 0; r < 4; ++r) {
              float val = acc[m][n][r];
              if (biasRow) val += biasRow[m0 + pass * 64 + rl0 + r];
              ft[(rl0 + r) * 132 + cl] = val;
            }
          }
        }
      }
      __syncthreads();
      #pragma unroll
      for (int i = 0; i < 8; ++i) {
        int idx = i * 256 + tid;
        int rrow = idx >> 5, c4 = (idx & 31) << 2;
        float4 v = *(const float4*)&ft[rrow * 132 + c4];
        const float4 rv = xr[pass * 8 + i];
        v.x += rv.x; v.y += rv.y; v.z += rv.z; v.w += rv.w;
        size_t gidx = (size_t)(m0 + pass * 64 + rrow) * ldc + (n0 + c4);
        *(float4*)&Cf[(size_t)bz * sC + gidx] = v;
      }
    }
  }
}

#define GEMM_ARGS const unsigned short* A, const unsigned short* Bm, void* Cm,            \
                  const float* biasRow, const float* biasCol, const float* Res,            \
                  int K, int lda, int ldb, int ldc, float scale,                           \
                  long long sA, long long sB, long long sC, long long sRes
#define GEMM_PASS A, Bm, Cm, biasRow, biasCol, Res, K, lda, ldb, ldc, scale, sA, sB, sC, sRes

__global__ __launch_bounds__(256) void gemm_qkv(GEMM_ARGS) { gemm_body<0>(GEMM_PASS); }
__global__ __launch_bounds__(256) void gemm_res(GEMM_ARGS) { gemm_body<3>(GEMM_PASS); }

// ================= S-GEMM fp8: 256x128-tile, BK=64, dbuf, 8 waves, exp->fp8 epilogue =================
// A=q8, B=k8 (1024B rows), fp8 x fp8 MFMA. LDS rows = 64B (4x 16B chunks).
// Swizzle f(r) = (r^(r>>2))&3 both-sides: 4*(r&1)+(c^f) injective over 8 rows -> 2-way free.
__global__ __launch_bounds__(512)
void gemm_s8(const unsigned char* __restrict__ A, const unsigned char* __restrict__ Bm,
             unsigned char* __restrict__ C,
             int K, int lda, int ldb, int ldc, float scale,
             long long sA, long long sB, long long sC) {
  const int nbx = gridDim.x, nby = gridDim.y;
  const int nb = nbx * nby * gridDim.z;
  int lin = (blockIdx.z * nby + blockIdx.y) * nbx + blockIdx.x;
  int bx, by, bz;
  if ((nb & 7) == 0) {
    int logical = (lin & 7) * (nb >> 3) + (lin >> 3);
    bx = logical % nbx;
    int t = logical / nbx;
    by = t % nby;
    bz = t / nby;
  } else { bx = blockIdx.x; by = blockIdx.y; bz = blockIdx.z; }

  const unsigned char* __restrict__ Ab = A + (size_t)bz * sA;
  const unsigned char* __restrict__ Bb = Bm + (size_t)bz * sB;
  unsigned char* __restrict__ Cb = C + (size_t)bz * sC;
  const int m0 = by * 256, n0 = bx * 128;

  __shared__ __align__(16) unsigned char smA[2][256 * 64];   // 32 KB
  __shared__ __align__(16) unsigned char smB[2][128 * 64];   // 16 KB

  const int tid = threadIdx.x, wave = tid >> 6, lane = tid & 63;
  const int wr = (wave >> 1) * 64;                  // 4 M-groups of 64
  const int wc = (wave & 1) * 64;                   // 2 N-groups of 64
  const int lr = lane & 15, lkc = lane >> 4;
  f32x4 acc[4][4] = {};

  // staging: A 16KB = 1024 16B-chunks -> 2/thread; B 512 chunks -> 1/thread
  int aRow[2], aCol[2];
  #pragma unroll
  for (int it = 0; it < 2; ++it) {
    int chunk = it * 512 + tid;
    int row = chunk >> 2, cc = chunk & 3;
    aRow[it] = row;
    aCol[it] = ((cc ^ swz8(row)) << 4);
  }
  const int bRow = tid >> 2;
  const int bCol = (((tid & 3) ^ swz8(bRow)) << 4);

  #define STG8(buf, kt)                                                                       \
    { _Pragma("unroll")                                                                       \
      for (int it = 0; it < 2; ++it)                                                          \
        __builtin_amdgcn_global_load_lds(                                                     \
            (const AS1 unsigned int*)(Ab + (size_t)(m0 + aRow[it]) * lda + (kt) + aCol[it]),  \
            (AS3 unsigned int*)(&smA[buf][0] + (size_t)(it * 512 + tid) * 16), 16, 0, 0);     \
      __builtin_amdgcn_global_load_lds(                                                       \
          (const AS1 unsigned int*)(Bb + (size_t)(n0 + bRow) * ldb + (kt) + bCol),            \
          (AS3 unsigned int*)(&smB[buf][0] + (size_t)tid * 16), 16, 0, 0);                    \
    }

  STG8(0, 0);
  __syncthreads();
  int cur = 0;
  for (int kt = 0; kt < K; kt += 64) {
    if (kt + 64 < K) STG8(cur ^ 1, kt + 64);
    #pragma unroll
    for (int s = 0; s < 2; ++s) {
      const int o = s * 32 + lkc * 8;
      long af[4], bfv[4];
      #pragma unroll
      for (int m = 0; m < 4; ++m) {
        int r = wr + m * 16 + lr;
        af[m] = *(const long*)&smA[cur][r * 64 + ((((o >> 4) ^ swz8(r)) << 4) | (o & 15))];
      }
      #pragma unroll
      for (int n = 0; n < 4; ++n) {
        int rb = wc + n * 16 + lr;
        bfv[n] = *(const long*)&smB[cur][rb * 64 + ((((o >> 4) ^ swz8(rb)) << 4) | (o & 15))];
      }
      #pragma unroll
      for (int m = 0; m < 4; ++m)
        #pragma unroll
        for (int n = 0; n < 4; ++n)
          acc[m][n] = __builtin_amdgcn_mfma_f32_16x16x32_fp8_fp8(af[m], bfv[n], acc[m][n], 0, 0, 0);
    }
    __syncthreads();
    cur ^= 1;
  }
  #undef STG8

  const int r0 = (lane >> 4) * 4, ccol = lane & 15;
  #pragma unroll
  for (int m = 0; m < 4; ++m) {
    const int gm = m0 + wr + m * 16 + r0;
    #pragma unroll
    for (int n = 0; n < 4; ++n) {
      const int gn = n0 + wc + n * 16 + ccol;
      #pragma unroll
      for (int r = 0; r < 4; ++r) {
        float val = __expf(acc[m][n][r] * scale);
        Cb[(size_t)(gm + r) * ldc + gn] = f2fp8(val);
      }
    }
  }
}

// ================= PV fp8: 128x128-tile, BK=64, dbuf, 4 waves, fused denominator =================
// A=P8 (4096B rows), B=vT8 (4096B rows). acc += P.V^T; acc_d += P.1 (fp8 1.0 = 0x38).
// LDS = 2*(128*64)*2 = 32KB -> 4 blocks/CU. Swizzle f(r) = (r^(r>>2))&3 both-sides.
__global__ __launch_bounds__(256)
void gemm_pv8(const unsigned char* __restrict__ A, const unsigned char* __restrict__ Bm,
              unsigned short* __restrict__ C,
              int K, int lda, int ldb, int ldc,
              long long sA, long long sB, long long sC) {
  const int nbx = gridDim.x, nby = gridDim.y;
  const int nb = nbx * nby * gridDim.z;
  int lin = (blockIdx.z * nby + blockIdx.y) * nbx + blockIdx.x;
  int bx, by, bz;
  if ((nb & 7) == 0) {
    int logical = (lin & 7) * (nb >> 3) + (lin >> 3);
    bx = logical % nbx;
    int t = logical / nbx;
    by = t % nby;
    bz = t / nby;
  } else { bx = blockIdx.x; by = blockIdx.y; bz = blockIdx.z; }

  const unsigned char* __restrict__ Ab = A + (size_t)bz * sA;
  const unsigned char* __restrict__ Bb = Bm + (size_t)bz * sB;
  unsigned short* __restrict__ Cb = C + (size_t)bz * sC;
  const int m0 = by * 128, n0 = bx * 128;

  __shared__ __align__(16) unsigned char pA[2][128 * 64];
  __shared__ __align__(16) unsigned char pB[2][128 * 64];

  const int tid = threadIdx.x, wave = tid >> 6, lane = tid & 63;
  const int wr = (wave >> 1) * 64, wc = (wave & 1) * 64;
  const int lr = lane & 15, lkc = lane >> 4;
  f32x4 acc[4][4] = {};
  f32x4 acc_d[4] = {};
  const long ones8 = 0x3838383838383838LL;           // 8x fp8 e4m3 1.0

  // staging: 8KB = 512 16B-chunks per tensor -> 2/thread each
  int sRow[2], sCol[2];
  #pragma unroll
  for (int it = 0; it < 2; ++it) {
    int chunk = it * 256 + tid;
    int row = chunk >> 2, cc = chunk & 3;
    sRow[it] = row;
    sCol[it] = ((cc ^ swz8(row)) << 4);
  }

  #define STGP(buf, kt)                                                                       \
    { _Pragma("unroll")                                                                       \
      for (int it = 0; it < 2; ++it) {                                                        \
        __builtin_amdgcn_global_load_lds(                                                     \
            (const AS1 unsigned int*)(Ab + (size_t)(m0 + sRow[it]) * lda + (kt) + sCol[it]),  \
            (AS3 unsigned int*)(&pA[buf][0] + (size_t)(it * 256 + tid) * 16), 16, 0, 0);      \
        __builtin_amdgcn_global_load_lds(                                                     \
            (const AS1 unsigned int*)(Bb + (size_t)(n0 + sRow[it]) * ldb + (kt) + sCol[it]),  \
            (AS3 unsigned int*)(&pB[buf][0] + (size_t)(it * 256 + tid) * 16), 16, 0, 0);      \
      }                                                                                       \
    }

  STGP(0, 0);
  __syncthreads();
  int cur = 0;
  for (int kt = 0; kt < K; kt += 64) {
    if (kt + 64 < K) STGP(cur ^ 1, kt + 64);
    #pragma unroll
    for (int s = 0; s < 2; ++s) {
      const int o = s * 32 + lkc * 8;
      long af[4], bfv[4];
      #pragma unroll
      for (int m = 0; m < 4; ++m) {
        int r = wr + m * 16 + lr;
        af[m] = *(const long*)&pA[cur][r * 64 + ((((o >> 4) ^ swz8(r)) << 4) | (o & 15))];
      }
      #pragma unroll
      for (int n = 0; n < 4; ++n) {
        int rb = wc + n * 16 + lr;
        bfv[n] = *(const long*)&pB[cur][rb * 64 + ((((o >> 4) ^ swz8(rb)) << 4) | (o & 15))];
      }
      #pragma unroll
      for (int m = 0; m < 4; ++m) {
        #pragma unroll
        for (int n = 0; n < 4; ++n)
          acc[m][n] = __builtin_amdgcn_mfma_f32_16x16x32_fp8_fp8(af[m], bfv[n], acc[m][n], 0, 0, 0);
        acc_d[m] = __builtin_amdgcn_mfma_f32_16x16x32_fp8_fp8(af[m], ones8, acc_d[m], 0, 0, 0);
      }
    }
    __syncthreads();
    cur ^= 1;
  }
  #undef STGP

  const int r0 = (lane >> 4) * 4, ccol = lane & 15;
  #pragma unroll
  for (int m = 0; m < 4; ++m) {
    const int gm = m0 + wr + m * 16 + r0;
    const float inv0 = 1.f / acc_d[m][0];
    const float inv1 = 1.f / acc_d[m][1];
    const float inv2 = 1.f / acc_d[m][2];
    const float inv3 = 1.f / acc_d[m][3];
    #pragma unroll
    for (int n = 0; n < 4; ++n) {
      const int gn = n0 + wc + n * 16 + ccol;
      #pragma unroll
      for (int r = 0; r < 4; ++r) {
        float val = acc[m][n][r] * (r == 0 ? inv0 : r == 1 ? inv1 : r == 2 ? inv2 : inv3);
        Cb[(size_t)(gm + r) * ldc + gn] = f2bf(val);
      }
    }
  }
}

extern "C" void kernel_launch(void* const* d_in, const int* in_sizes, int n_in,
                              void* d_out, int out_size, void* d_ws, size_t ws_size,
                              hipStream_t stream) {
  (void)in_sizes; (void)n_in; (void)out_size;
  const float* x   = (const float*)d_in[0];
  const float* nsc = (const float*)d_in[1];
  const float* nbi = (const float*)d_in[2];
  const float* wq  = (const float*)d_in[3];
  const float* bq  = (const float*)d_in[4];
  const float* wk  = (const float*)d_in[5];
  const float* bk  = (const float*)d_in[6];
  const float* wv  = (const float*)d_in[7];
  const float* bv  = (const float*)d_in[8];
  const float* wp  = (const float*)d_in[9];
  const float* bp  = (const float*)d_in[10];
  float* out = (float*)d_out;
  char* ws = (char*)d_ws;

  const size_t nW = (size_t)CCH * CCH;
  unsigned short* wb = (unsigned short*)ws;            // 2 MB (bf16 weights)
  float* bcat = (float*)(ws + 4 * nW * 2);             // 6 KB
  float* stats = bcat + 1536;                          // 2 KB
  const size_t o_h = 4 * nW * 2 + 16384;
  unsigned short* ht = (unsigned short*)(ws + o_h);    // 32 MB (b, p, 512) bf16
  unsigned char* qk8 = (unsigned char*)(ht + (size_t)BATCH * HWP * CCH);   // 32 MB (b,p,1024) fp8
  unsigned char* vT8 = qk8 + (size_t)BATCH * HWP * 1024;                   // 16 MB (b,c,p) fp8
  unsigned char* P8  = vT8 + (size_t)BATCH * CCH * HWP;                    // G*16 MB (slice)
  unsigned short* ot = ht;                             // alias: ht dead after QKV gemm
  const size_t o_P8 = o_h + (size_t)BATCH * HWP * CCH * 2
                    + (size_t)BATCH * HWP * 1024 + (size_t)BATCH * CCH * HWP;
  int G = 8;
  while (G > 1 && o_P8 + (size_t)G * HWP * HWP > ws_size) G >>= 1;

  const long long sHC  = (long long)HWP * CCH;         // bf16 elements / batch
  const long long sQK8 = (long long)HWP * 1024;        // bytes / batch
  const long long sV8  = (long long)CCH * HWP;         // bytes / batch
  const long long sP8  = (long long)HWP * HWP;         // bytes / batch

  cvt_w<<<dim3((unsigned)((nW + 255) / 256)), dim3(256), 0, stream>>>(
      wq, wk, wv, wp, bq, bk, bv, wb, bcat);
  gn_stats<<<dim3(BATCH * NG), dim3(256), 0, stream>>>(x, stats);
  gn_apply<<<dim3(HWP / 64, CCH / 64, BATCH), dim3(256), 0, stream>>>(x, stats, nsc, nbi, ht);

  // fused QKV (fp8 out): Q,K -> qk8 (b,p,1024); V -> vT8 transposed (b,c,p)
  gemm_qkv<<<dim3(1536 / 128, HWP / 128, BATCH), dim3(256), 0, stream>>>(
      ht, wb, qk8, nullptr, bcat, (const float*)vT8,
      CCH, CCH, CCH, 1024, 1.f, sHC, 0, sQK8, sV8);

  const float sc = 0.04419417382415922f;               // 512^-0.5
  for (int b0 = 0; b0 < BATCH; b0 += G) {
    // P8[d][e] = fp8(exp(sc * q8[d].k8[e]))
    gemm_s8<<<dim3(HWP / 128, HWP / 256, G), dim3(512), 0, stream>>>(
        qk8 + (size_t)b0 * sQK8, qk8 + 512 + (size_t)b0 * sQK8, P8,
        CCH, 1024, 1024, HWP, sc, sQK8, sQK8, sP8);
    // ot[d][c] = (P8[d].vT8[c]) / (P8[d].1)
    gemm_pv8<<<dim3(CCH / 128, HWP / 128, G), dim3(256), 0, stream>>>(
        P8, vT8 + (size_t)b0 * sV8, ot + (size_t)b0 * sHC,
        HWP, HWP, HWP, CCH, sP8, sV8, sHC);
  }

  // final: out[o][p] = x[o][p] + bp[o] + sum_c wp[o][c] ot[p][c]   (bf16 engine, f32 out)
  gemm_res<<<dim3(HWP / 128, CCH / 128, BATCH), dim3(256), 0, stream>>>(
      wb + 3 * nW, ot, out, bp, nullptr, x,
      CCH, CCH, CCH, HWP, 1.f, 0, sHC, sHC, sHC);
}

// Round 19
// 459.920 us; speedup vs baseline: 1.5598x; 1.0525x over previous
//
#include <hip/hip_runtime.h>
#include <hip/hip_fp8.h>

// AttnBlock2D: GroupNorm -> fused QKV -> 1-head attention (hw=4096, dh=512) -> proj + residual
// R19 = R18 (484us) + gemm_pv8 reshaped to BM=128 x BN=256 (8 waves, 512 thr, LDS 48KB):
//       P8 panels (16MB/batch, L3-served since > 4MB per-XCD L2) were re-read N/BN=4x;
//       BN=256 halves that to 2x (L3 traffic 512->256MB) and cuts staged bytes 1GB->768MB.
//       Same dbuf skeleton. Everything else unchanged from R18.

#define BATCH 8
#define CCH 512
#define HWP 4096
#define NG 32

#define AS1 __attribute__((address_space(1)))
#define AS3 __attribute__((address_space(3)))

typedef __attribute__((ext_vector_type(8))) short s16x8;
typedef __attribute__((ext_vector_type(4))) float f32x4;

__device__ __forceinline__ unsigned short f2bf(float f) {
  union { float f; unsigned u; } v; v.f = f;
  return (unsigned short)((v.u + 0x7FFFu + ((v.u >> 16) & 1u)) >> 16);
}
__device__ __forceinline__ unsigned char f2fp8(float f) {
  __hip_fp8_e4m3 h(f);                               // OCP e4m3, RNE+sat
  return (unsigned char)h.__x;
}
__device__ __forceinline__ int swz8(int r) {         // fp8 chunk swizzle
  return (r ^ (r >> 2)) & 3;
}

// ---------------- weight convert f32 -> bf16 (4 matrices) + qkv bias concat ----------------
__global__ void cvt_w(const float* __restrict__ w0, const float* __restrict__ w1,
                      const float* __restrict__ w2, const float* __restrict__ w3,
                      const float* __restrict__ bq, const float* __restrict__ bk,
                      const float* __restrict__ bv,
                      unsigned short* __restrict__ out, float* __restrict__ bcat) {
  int i = blockIdx.x * 256 + threadIdx.x;
  const int n = CCH * CCH;
  if (i < CCH) {
    bcat[i]           = bq[i];
    bcat[CCH + i]     = bk[i];
    bcat[2 * CCH + i] = bv[i];
  }
  if (i < n) {
    out[i]         = f2bf(w0[i]);
    out[n + i]     = f2bf(w1[i]);
    out[2 * n + i] = f2bf(w2[i]);
    out[3 * n + i] = f2bf(w3[i]);
  }
}

// ---------------- GroupNorm stats: one block per (b,g) ----------------
__global__ void gn_stats(const float* __restrict__ x, float* __restrict__ stats) {
  const int bg = blockIdx.x;
  const float* base = x + (size_t)bg * (16 * HWP);
  float s = 0.f, sq = 0.f;
  for (int i = threadIdx.x; i < 16 * HWP / 4; i += 256) {
    float4 v = ((const float4*)base)[i];
    s += v.x + v.y + v.z + v.w;
    sq += v.x * v.x + v.y * v.y + v.z * v.z + v.w * v.w;
  }
  #pragma unroll
  for (int o = 32; o; o >>= 1) { s += __shfl_xor(s, o); sq += __shfl_xor(sq, o); }
  __shared__ float ls[4], lq[4];
  const int wv = threadIdx.x >> 6;
  if ((threadIdx.x & 63) == 0) { ls[wv] = s; lq[wv] = sq; }
  __syncthreads();
  if (threadIdx.x == 0) {
    s = ls[0] + ls[1] + ls[2] + ls[3];
    sq = lq[0] + lq[1] + lq[2] + lq[3];
    const float inv_n = 1.f / (16.f * HWP);
    float mean = s * inv_n;
    float var = sq * inv_n - mean * mean;
    stats[2 * bg] = mean;
    stats[2 * bg + 1] = rsqrtf(var + 1e-5f);
  }
}

// ---------------- GroupNorm apply + transpose -> h_t (hw, c) bf16 ----------------
__global__ void gn_apply(const float* __restrict__ x, const float* __restrict__ stats,
                         const float* __restrict__ scale, const float* __restrict__ bias,
                         unsigned short* __restrict__ ht) {
  const int p0 = blockIdx.x * 64, c0 = blockIdx.y * 64, b = blockIdx.z;
  const int tx = threadIdx.x & 63, ty = threadIdx.x >> 6;
  __shared__ unsigned short tile[64][65];
  #pragma unroll 4
  for (int j = 0; j < 16; ++j) {
    int cl = ty + j * 4;
    int c = c0 + cl;
    int g = c >> 4;
    float mean = stats[(b * NG + g) * 2];
    float rstd = stats[(b * NG + g) * 2 + 1];
    float v = x[((size_t)(b * CCH + c)) * HWP + p0 + tx];
    v = (v - mean) * rstd * scale[c] + bias[c];
    tile[cl][tx] = f2bf(v);
  }
  __syncthreads();
  #pragma unroll 4
  for (int j = 0; j < 16; ++j) {
    int pl = ty + j * 4;
    ht[((size_t)b * HWP + p0 + pl) * CCH + c0 + tx] = tile[tx][pl];
  }
}

// ---------------- NT GEMM (R3 engine): 128x128, BK=64, dbuf, bf16 MFMA ----------------
// MODE 0: fp8 out. n0<1024: Q/K -> qk8 (ldc=1024B rows). n0>=1024: V -> byte-LDS-bounce
//         transpose -> vT8 (=Res, stride sRes bytes).   (fused QKV + V^T, all fp8)
// MODE 3: f32 out, + biasRow + Res(prefetched to regs), coalesced epilogue (final proj)
template<int MODE>
__device__ __forceinline__ void gemm_body(
    const unsigned short* __restrict__ A, const unsigned short* __restrict__ Bm,
    void* __restrict__ Cm, const float* __restrict__ biasRow,
    const float* __restrict__ biasCol, const float* __restrict__ Res,
    int K, int lda, int ldb, int ldc, float scale,
    long long sA, long long sB, long long sC, long long sRes) {
  // --- bijective XCD swizzle ---
  const int nbx = gridDim.x, nby = gridDim.y;
  const int nb = nbx * nby * gridDim.z;
  int lin = (blockIdx.z * nby + blockIdx.y) * nbx + blockIdx.x;
  int bx, by, bz;
  if ((nb & 7) == 0) {
    int logical = (lin & 7) * (nb >> 3) + (lin >> 3);
    bx = logical % nbx;
    int t = logical / nbx;
    by = t % nby;
    bz = t / nby;
  } else { bx = blockIdx.x; by = blockIdx.y; bz = blockIdx.z; }

  const unsigned short* Ab = A + (size_t)bz * sA;
  const unsigned short* Bb = Bm + (size_t)bz * sB;
  const int m0 = by * 128, n0 = bx * 128;
  __shared__ __align__(16) unsigned short sm[2][2][128 * 64];  // [A/B][dbuf][tile]
  const int tid = threadIdx.x, wave = tid >> 6, lane = tid & 63;
  const int wr = (wave >> 1) * 64, wc = (wave & 1) * 64;
  const int lr = lane & 15, lkc = lane >> 4;
  f32x4 acc[4][4] = {};

  // MODE 3: prefetch the residual tile into registers (read hides under the K-loop)
  float4 xr[16];
  if (MODE == 3) {
    #pragma unroll
    for (int pass = 0; pass < 2; ++pass)
      #pragma unroll
      for (int i = 0; i < 8; ++i) {
        int idx = i * 256 + tid;
        int rrow = idx >> 5, c4 = (idx & 31) << 2;
        size_t gidx = (size_t)(m0 + pass * 64 + rrow) * ldc + (n0 + c4);
        xr[pass * 8 + i] = *(const float4*)&Res[(size_t)bz * sRes + gidx];
      }
  }

  const int chunkBase = wave * 64 + lane;
  int srow[4], sc8[4];
  #pragma unroll
  for (int it = 0; it < 4; ++it) {
    int chunk = it * 256 + chunkBase;
    srow[it] = chunk >> 3;
    sc8[it] = (((chunk & 7) ^ (srow[it] & 7)) * 8);
  }

  #define STAGE(buf, kt)                                                                 \
    { _Pragma("unroll")                                                                  \
      for (int it = 0; it < 4; ++it) {                                                   \
        __builtin_amdgcn_global_load_lds(                                                \
            (const AS1 unsigned int*)(Ab + (size_t)(m0 + srow[it]) * lda + (kt) + sc8[it]), \
            (AS3 unsigned int*)(&sm[0][buf][0] + (size_t)(it * 256 + wave * 64) * 8), 16, 0, 0); \
        __builtin_amdgcn_global_load_lds(                                                \
            (const AS1 unsigned int*)(Bb + (size_t)(n0 + srow[it]) * ldb + (kt) + sc8[it]), \
            (AS3 unsigned int*)(&sm[1][buf][0] + (size_t)(it * 256 + wave * 64) * 8), 16, 0, 0); \
      }                                                                                  \
    }

  STAGE(0, 0);
  __syncthreads();
  int cur = 0;
  for (int kt = 0; kt < K; kt += 64) {
    if (kt + 64 < K) STAGE(cur ^ 1, kt + 64);
    #pragma unroll
    for (int kk = 0; kk < 64; kk += 32) {
      const int jbase = (kk >> 3) + lkc;
      s16x8 af[4], bfv[4];
      #pragma unroll
      for (int m = 0; m < 4; ++m) {
        int r = wr + m * 16 + lr;
        af[m] = *(const s16x8*)&sm[0][cur][r * 64 + ((jbase ^ (r & 7)) << 3)];
      }
      #pragma unroll
      for (int n = 0; n < 4; ++n) {
        int r = wc + n * 16 + lr;
        bfv[n] = *(const s16x8*)&sm[1][cur][r * 64 + ((jbase ^ (r & 7)) << 3)];
      }
      #pragma unroll
      for (int m = 0; m < 4; ++m)
        #pragma unroll
        for (int n = 0; n < 4; ++n)
          acc[m][n] = __builtin_amdgcn_mfma_f32_16x16x32_bf16(af[m], bfv[n], acc[m][n], 0, 0, 0);
    }
    __syncthreads();
    cur ^= 1;
  }
  #undef STAGE

  const int r0 = (lane >> 4) * 4, ccol = lane & 15;
  if (MODE == 0) {
    if (n0 >= 1024) {
      // ---- V-block: fp8 transpose via byte LDS bounce [128][136] -> vT8 (b,c,p) ----
      unsigned char* ltb = (unsigned char*)&sm[0][0][0];  // 17408 B
      #pragma unroll
      for (int m = 0; m < 4; ++m) {
        const int gm_l = wr + m * 16 + r0;                // local p-row (mult of 4)
        #pragma unroll
        for (int n = 0; n < 4; ++n) {
          const int gn_l = wc + n * 16 + ccol;            // local o-col
          const float bc = biasCol ? biasCol[n0 + gn_l] : 0.f;
          union { unsigned char b[4]; unsigned u; } pk;
          #pragma unroll
          for (int r = 0; r < 4; ++r) pk.b[r] = f2fp8(acc[m][n][r] * scale + bc);
          *(unsigned*)&ltb[gn_l * 136 + gm_l] = pk.u;     // transposed: [o][p]
        }
      }
      __syncthreads();
      unsigned char* vout = (unsigned char*)Res;          // vT8 base
      const int c0v = n0 - 1024;
      #pragma unroll
      for (int i = 0; i < 8; ++i) {
        int idx = i * 256 + tid;
        int orow = idx >> 4, pc = (idx & 15) * 8;
        unsigned long long v8 = *(const unsigned long long*)&ltb[orow * 136 + pc];
        *(unsigned long long*)&vout[(size_t)bz * sRes + (size_t)(c0v + orow) * HWP + m0 + pc] = v8;
      }
    } else {
      // ---- Q/K block: fp8 out to qk8 (ldc bytes per p-row) ----
      unsigned char* C8 = (unsigned char*)Cm;
      #pragma unroll
      for (int m = 0; m < 4; ++m) {
        const int gm = m0 + wr + m * 16 + r0;
        #pragma unroll
        for (int n = 0; n < 4; ++n) {
          const int gn = n0 + wc + n * 16 + ccol;
          const float bc = biasCol ? biasCol[gn] : 0.f;
          #pragma unroll
          for (int r = 0; r < 4; ++r) {
            float val = acc[m][n][r] * scale + bc;
            C8[(size_t)bz * sC + (size_t)(gm + r) * ldc + gn] = f2fp8(val);
          }
        }
      }
    }
  } else {
    // f32 out: coalesced epilogue via LDS bounce; residual already in xr registers
    float* ft = (float*)&sm[0][0][0];
    float* Cf = (float*)Cm;
    #pragma unroll
    for (int pass = 0; pass < 2; ++pass) {
      __syncthreads();
      if ((wave >> 1) == pass) {
        #pragma unroll
        for (int m = 0; m < 4; ++m) {
          const int rl0 = m * 16 + (lane >> 4) * 4;
          #pragma unroll
          for (int n = 0; n < 4; ++n) {
            const int cl = wc + n * 16 + (lane & 15);
            #pragma unroll
            for (int r = 0; r < 4; ++r) {
              float val = acc[m][n][r];
              if (biasRow) val += biasRow[m0 + pass * 64 + rl0 + r];
              ft[(rl0 + r) * 132 + cl] = val;
            }
          }
        }
      }
      __syncthreads();
      #pragma unroll
      for (int i = 0; i < 8; ++i) {
        int idx = i * 256 + tid;
        int rrow = idx >> 5, c4 = (idx & 31) << 2;
        float4 v = *(const float4*)&ft[rrow * 132 + c4];
        const float4 rv = xr[pass * 8 + i];
        v.x += rv.x; v.y += rv.y; v.z += rv.z; v.w += rv.w;
        size_t gidx = (size_t)(m0 + pass * 64 + rrow) * ldc + (n0 + c4);
        *(float4*)&Cf[(size_t)bz * sC + gidx] = v;
      }
    }
  }
}

#define GEMM_ARGS const unsigned short* A, const unsigned short* Bm, void* Cm,            \
                  const float* biasRow, const float* biasCol, const float* Res,            \
                  int K, int lda, int ldb, int ldc, float scale,                           \
                  long long sA, long long sB, long long sC, long long sRes
#define GEMM_PASS A, Bm, Cm, biasRow, biasCol, Res, K, lda, ldb, ldc, scale, sA, sB, sC, sRes

__global__ __launch_bounds__(256) void gemm_qkv(GEMM_ARGS) { gemm_body<0>(GEMM_PASS); }
__global__ __launch_bounds__(256) void gemm_res(GEMM_ARGS) { gemm_body<3>(GEMM_PASS); }

// ================= S-GEMM fp8: 256x128-tile, BK=64, dbuf, 8 waves, exp->fp8 epilogue =================
__global__ __launch_bounds__(512)
void gemm_s8(const unsigned char* __restrict__ A, const unsigned char* __restrict__ Bm,
             unsigned char* __restrict__ C,
             int K, int lda, int ldb, int ldc, float scale,
             long long sA, long long sB, long long sC) {
  const int nbx = gridDim.x, nby = gridDim.y;
  const int nb = nbx * nby * gridDim.z;
  int lin = (blockIdx.z * nby + blockIdx.y) * nbx + blockIdx.x;
  int bx, by, bz;
  if ((nb & 7) == 0) {
    int logical = (lin & 7) * (nb >> 3) + (lin >> 3);
    bx = logical % nbx;
    int t = logical / nbx;
    by = t % nby;
    bz = t / nby;
  } else { bx = blockIdx.x; by = blockIdx.y; bz = blockIdx.z; }

  const unsigned char* __restrict__ Ab = A + (size_t)bz * sA;
  const unsigned char* __restrict__ Bb = Bm + (size_t)bz * sB;
  unsigned char* __restrict__ Cb = C + (size_t)bz * sC;
  const int m0 = by * 256, n0 = bx * 128;

  __shared__ __align__(16) unsigned char smA[2][256 * 64];   // 32 KB
  __shared__ __align__(16) unsigned char smB[2][128 * 64];   // 16 KB

  const int tid = threadIdx.x, wave = tid >> 6, lane = tid & 63;
  const int wr = (wave >> 1) * 64;                  // 4 M-groups of 64
  const int wc = (wave & 1) * 64;                   // 2 N-groups of 64
  const int lr = lane & 15, lkc = lane >> 4;
  f32x4 acc[4][4] = {};

  // staging: A 16KB = 1024 16B-chunks -> 2/thread; B 512 chunks -> 1/thread
  int aRow[2], aCol[2];
  #pragma unroll
  for (int it = 0; it < 2; ++it) {
    int chunk = it * 512 + tid;
    int row = chunk >> 2, cc = chunk & 3;
    aRow[it] = row;
    aCol[it] = ((cc ^ swz8(row)) << 4);
  }
  const int bRow = tid >> 2;
  const int bCol = (((tid & 3) ^ swz8(bRow)) << 4);

  #define STG8(buf, kt)                                                                       \
    { _Pragma("unroll")                                                                       \
      for (int it = 0; it < 2; ++it)                                                          \
        __builtin_amdgcn_global_load_lds(                                                     \
            (const AS1 unsigned int*)(Ab + (size_t)(m0 + aRow[it]) * lda + (kt) + aCol[it]),  \
            (AS3 unsigned int*)(&smA[buf][0] + (size_t)(it * 512 + tid) * 16), 16, 0, 0);     \
      __builtin_amdgcn_global_load_lds(                                                       \
          (const AS1 unsigned int*)(Bb + (size_t)(n0 + bRow) * ldb + (kt) + bCol),            \
          (AS3 unsigned int*)(&smB[buf][0] + (size_t)tid * 16), 16, 0, 0);                    \
    }

  STG8(0, 0);
  __syncthreads();
  int cur = 0;
  for (int kt = 0; kt < K; kt += 64) {
    if (kt + 64 < K) STG8(cur ^ 1, kt + 64);
    #pragma unroll
    for (int s = 0; s < 2; ++s) {
      const int o = s * 32 + lkc * 8;
      long af[4], bfv[4];
      #pragma unroll
      for (int m = 0; m < 4; ++m) {
        int r = wr + m * 16 + lr;
        af[m] = *(const long*)&smA[cur][r * 64 + ((((o >> 4) ^ swz8(r)) << 4) | (o & 15))];
      }
      #pragma unroll
      for (int n = 0; n < 4; ++n) {
        int rb = wc + n * 16 + lr;
        bfv[n] = *(const long*)&smB[cur][rb * 64 + ((((o >> 4) ^ swz8(rb)) << 4) | (o & 15))];
      }
      #pragma unroll
      for (int m = 0; m < 4; ++m)
        #pragma unroll
        for (int n = 0; n < 4; ++n)
          acc[m][n] = __builtin_amdgcn_mfma_f32_16x16x32_fp8_fp8(af[m], bfv[n], acc[m][n], 0, 0, 0);
    }
    __syncthreads();
    cur ^= 1;
  }
  #undef STG8

  const int r0 = (lane >> 4) * 4, ccol = lane & 15;
  #pragma unroll
  for (int m = 0; m < 4; ++m) {
    const int gm = m0 + wr + m * 16 + r0;
    #pragma unroll
    for (int n = 0; n < 4; ++n) {
      const int gn = n0 + wc + n * 16 + ccol;
      #pragma unroll
      for (int r = 0; r < 4; ++r) {
        float val = __expf(acc[m][n][r] * scale);
        Cb[(size_t)(gm + r) * ldc + gn] = f2fp8(val);
      }
    }
  }
}

// ================= PV fp8: 128x256-tile, BK=64, dbuf, 8 waves, fused denominator =================
// A=P8 (4096B rows, M=4096), B=vT8 (4096B rows, N=512). BN=256 halves P8 panel re-reads
// (L3-served: 16MB/batch > 4MB per-XCD L2). acc += P.V^T; acc_d += P.1 (fp8 1.0 = 0x38).
// LDS = 2*(128+256)*64 = 48KB. 512 thr, 8 waves (2M x 4N), wave = 64x64.
__global__ __launch_bounds__(512)
void gemm_pv8(const unsigned char* __restrict__ A, const unsigned char* __restrict__ Bm,
              unsigned short* __restrict__ C,
              int K, int lda, int ldb, int ldc,
              long long sA, long long sB, long long sC) {
  const int nbx = gridDim.x, nby = gridDim.y;
  const int nb = nbx * nby * gridDim.z;
  int lin = (blockIdx.z * nby + blockIdx.y) * nbx + blockIdx.x;
  int bx, by, bz;
  if ((nb & 7) == 0) {
    int logical = (lin & 7) * (nb >> 3) + (lin >> 3);
    bx = logical % nbx;
    int t = logical / nbx;
    by = t % nby;
    bz = t / nby;
  } else { bx = blockIdx.x; by = blockIdx.y; bz = blockIdx.z; }

  const unsigned char* __restrict__ Ab = A + (size_t)bz * sA;
  const unsigned char* __restrict__ Bb = Bm + (size_t)bz * sB;
  unsigned short* __restrict__ Cb = C + (size_t)bz * sC;
  const int m0 = by * 128, n0 = bx * 256;

  __shared__ __align__(16) unsigned char pA[2][128 * 64];    // 16 KB
  __shared__ __align__(16) unsigned char pB[2][256 * 64];    // 32 KB

  const int tid = threadIdx.x, wave = tid >> 6, lane = tid & 63;
  const int wr = (wave >> 2) * 64;                  // 2 M-groups of 64
  const int wc = (wave & 3) * 64;                   // 4 N-groups of 64
  const int lr = lane & 15, lkc = lane >> 4;
  f32x4 acc[4][4] = {};
  f32x4 acc_d[4] = {};
  const long ones8 = 0x3838383838383838LL;          // 8x fp8 e4m3 1.0

  // staging: A 8KB = 512 chunks -> 1/thread; B 16KB = 1024 chunks -> 2/thread
  const int aRow = tid >> 2;
  const int aCol = (((tid & 3) ^ swz8(aRow)) << 4);
  int bRow[2], bCol[2];
  #pragma unroll
  for (int it = 0; it < 2; ++it) {
    int chunk = it * 512 + tid;
    int row = chunk >> 2, cc = chunk & 3;
    bRow[it] = row;
    bCol[it] = ((cc ^ swz8(row)) << 4);
  }

  #define STGP(buf, kt)                                                                       \
    { __builtin_amdgcn_global_load_lds(                                                       \
          (const AS1 unsigned int*)(Ab + (size_t)(m0 + aRow) * lda + (kt) + aCol),            \
          (AS3 unsigned int*)(&pA[buf][0] + (size_t)tid * 16), 16, 0, 0);                     \
      _Pragma("unroll")                                                                       \
      for (int it = 0; it < 2; ++it)                                                          \
        __builtin_amdgcn_global_load_lds(                                                     \
            (const AS1 unsigned int*)(Bb + (size_t)(n0 + bRow[it]) * ldb + (kt) + bCol[it]),  \
            (AS3 unsigned int*)(&pB[buf][0] + (size_t)(it * 512 + tid) * 16), 16, 0, 0);      \
    }

  STGP(0, 0);
  __syncthreads();
  int cur = 0;
  for (int kt = 0; kt < K; kt += 64) {
    if (kt + 64 < K) STGP(cur ^ 1, kt + 64);
    #pragma unroll
    for (int s = 0; s < 2; ++s) {
      const int o = s * 32 + lkc * 8;
      long af[4], bfv[4];
      #pragma unroll
      for (int m = 0; m < 4; ++m) {
        int r = wr + m * 16 + lr;
        af[m] = *(const long*)&pA[cur][r * 64 + ((((o >> 4) ^ swz8(r)) << 4) | (o & 15))];
      }
      #pragma unroll
      for (int n = 0; n < 4; ++n) {
        int rb = wc + n * 16 + lr;
        bfv[n] = *(const long*)&pB[cur][rb * 64 + ((((o >> 4) ^ swz8(rb)) << 4) | (o & 15))];
      }
      #pragma unroll
      for (int m = 0; m < 4; ++m) {
        #pragma unroll
        for (int n = 0; n < 4; ++n)
          acc[m][n] = __builtin_amdgcn_mfma_f32_16x16x32_fp8_fp8(af[m], bfv[n], acc[m][n], 0, 0, 0);
        acc_d[m] = __builtin_amdgcn_mfma_f32_16x16x32_fp8_fp8(af[m], ones8, acc_d[m], 0, 0, 0);
      }
    }
    __syncthreads();
    cur ^= 1;
  }
  #undef STGP

  const int r0 = (lane >> 4) * 4, ccol = lane & 15;
  #pragma unroll
  for (int m = 0; m < 4; ++m) {
    const int gm = m0 + wr + m * 16 + r0;
    const float inv0 = 1.f / acc_d[m][0];
    const float inv1 = 1.f / acc_d[m][1];
    const float inv2 = 1.f / acc_d[m][2];
    const float inv3 = 1.f / acc_d[m][3];
    #pragma unroll
    for (int n = 0; n < 4; ++n) {
      const int gn = n0 + wc + n * 16 + ccol;
      #pragma unroll
      for (int r = 0; r < 4; ++r) {
        float val = acc[m][n][r] * (r == 0 ? inv0 : r == 1 ? inv1 : r == 2 ? inv2 : inv3);
        Cb[(size_t)(gm + r) * ldc + gn] = f2bf(val);
      }
    }
  }
}

extern "C" void kernel_launch(void* const* d_in, const int* in_sizes, int n_in,
                              void* d_out, int out_size, void* d_ws, size_t ws_size,
                              hipStream_t stream) {
  (void)in_sizes; (void)n_in; (void)out_size;
  const float* x   = (const float*)d_in[0];
  const float* nsc = (const float*)d_in[1];
  const float* nbi = (const float*)d_in[2];
  const float* wq  = (const float*)d_in[3];
  const float* bq  = (const float*)d_in[4];
  const float* wk  = (const float*)d_in[5];
  const float* bk  = (const float*)d_in[6];
  const float* wv  = (const float*)d_in[7];
  const float* bv  = (const float*)d_in[8];
  const float* wp  = (const float*)d_in[9];
  const float* bp  = (const float*)d_in[10];
  float* out = (float*)d_out;
  char* ws = (char*)d_ws;

  const size_t nW = (size_t)CCH * CCH;
  unsigned short* wb = (unsigned short*)ws;            // 2 MB (bf16 weights)
  float* bcat = (float*)(ws + 4 * nW * 2);             // 6 KB
  float* stats = bcat + 1536;                          // 2 KB
  const size_t o_h = 4 * nW * 2 + 16384;
  unsigned short* ht = (unsigned short*)(ws + o_h);    // 32 MB (b, p, 512) bf16
  unsigned char* qk8 = (unsigned char*)(ht + (size_t)BATCH * HWP * CCH);   // 32 MB (b,p,1024) fp8
  unsigned char* vT8 = qk8 + (size_t)BATCH * HWP * 1024;                   // 16 MB (b,c,p) fp8
  unsigned char* P8  = vT8 + (size_t)BATCH * CCH * HWP;                    // G*16 MB (slice)
  unsigned short* ot = ht;                             // alias: ht dead after QKV gemm
  const size_t o_P8 = o_h + (size_t)BATCH * HWP * CCH * 2
                    + (size_t)BATCH * HWP * 1024 + (size_t)BATCH * CCH * HWP;
  int G = 8;
  while (G > 1 && o_P8 + (size_t)G * HWP * HWP > ws_size) G >>= 1;

  const long long sHC  = (long long)HWP * CCH;         // bf16 elements / batch
  const long long sQK8 = (long long)HWP * 1024;        // bytes / batch
  const long long sV8  = (long long)CCH * HWP;         // bytes / batch
  const long long sP8  = (long long)HWP * HWP;         // bytes / batch

  cvt_w<<<dim3((unsigned)((nW + 255) / 256)), dim3(256), 0, stream>>>(
      wq, wk, wv, wp, bq, bk, bv, wb, bcat);
  gn_stats<<<dim3(BATCH * NG), dim3(256), 0, stream>>>(x, stats);
  gn_apply<<<dim3(HWP / 64, CCH / 64, BATCH), dim3(256), 0, stream>>>(x, stats, nsc, nbi, ht);

  // fused QKV (fp8 out): Q,K -> qk8 (b,p,1024); V -> vT8 transposed (b,c,p)
  gemm_qkv<<<dim3(1536 / 128, HWP / 128, BATCH), dim3(256), 0, stream>>>(
      ht, wb, qk8, nullptr, bcat, (const float*)vT8,
      CCH, CCH, CCH, 1024, 1.f, sHC, 0, sQK8, sV8);

  const float sc = 0.04419417382415922f;               // 512^-0.5
  for (int b0 = 0; b0 < BATCH; b0 += G) {
    // P8[d][e] = fp8(exp(sc * q8[d].k8[e]))
    gemm_s8<<<dim3(HWP / 128, HWP / 256, G), dim3(512), 0, stream>>>(
        qk8 + (size_t)b0 * sQK8, qk8 + 512 + (size_t)b0 * sQK8, P8,
        CCH, 1024, 1024, HWP, sc, sQK8, sQK8, sP8);
    // ot[d][c] = (P8[d].vT8[c]) / (P8[d].1)   (BN=256: P panels re-read 2x not 4x)
    gemm_pv8<<<dim3(CCH / 256, HWP / 128, G), dim3(512), 0, stream>>>(
        P8, vT8 + (size_t)b0 * sV8, ot + (size_t)b0 * sHC,
        HWP, HWP, HWP, CCH, sP8, sV8, sHC);
  }

  // final: out[o][p] = x[o][p] + bp[o] + sum_c wp[o][c] ot[p][c]   (bf16 engine, f32 out)
  gemm_res<<<dim3(HWP / 128, CCH / 128, BATCH), dim3(256), 0, stream>>>(
      wb + 3 * nW, ot, out, bp, nullptr, x,
      CCH, CCH, CCH, HWP, 1.f, 0, sHC, sHC, sHC);
}

// Round 21
// 453.021 us; speedup vs baseline: 1.5835x; 1.0152x over previous
//
#include <hip/hip_runtime.h>
#include <hip/hip_fp8.h>

// AttnBlock2D: GroupNorm -> fused QKV -> 1-head attention (hw=4096, dh=512) -> proj + residual
// R21 = R20 with SATURATION added to the HW fp8 path: v_cvt_pk_fp8_f32 (no CLAMP) maps
//       out-of-range -> NaN (e4m3fn has no inf); correlated Q/K tails push max score past
//       ln(448), so a few exp(s) overflowed -> NaN through PV (R20 failure). pk4_fp8 now
//       clamps to +-448 before converting (~2 VALU/val vs 15 for the software ctor).
//       Everything else identical to R20/R19.

#define BATCH 8
#define CCH 512
#define HWP 4096
#define NG 32

#define AS1 __attribute__((address_space(1)))
#define AS3 __attribute__((address_space(3)))

typedef __attribute__((ext_vector_type(8))) short s16x8;
typedef __attribute__((ext_vector_type(4))) float f32x4;

__device__ __forceinline__ unsigned short f2bf(float f) {
  union { float f; unsigned u; } v; v.f = f;
  return (unsigned short)((v.u + 0x7FFFu + ((v.u >> 16) & 1u)) >> 16);
}
__device__ __forceinline__ unsigned char f2fp8(float f) {
  __hip_fp8_e4m3 h(f);                               // OCP e4m3, RNE+sat (fallback path)
  return (unsigned char)h.__x;
}
// pack 4 floats -> 4 fp8 bytes (v0 in byte0); clamp to +-448 (e4m3 max) BEFORE HW convert
__device__ __forceinline__ float sat8(float v) {
  return fminf(fmaxf(v, -448.f), 448.f);
}
__device__ __forceinline__ unsigned pk4_fp8(float v0, float v1, float v2, float v3) {
#if __has_builtin(__builtin_amdgcn_cvt_pk_fp8_f32)
  int pk = __builtin_amdgcn_cvt_pk_fp8_f32(sat8(v0), sat8(v1), 0, false);   // bytes 0,1
  pk = __builtin_amdgcn_cvt_pk_fp8_f32(sat8(v2), sat8(v3), pk, true);       // bytes 2,3
  return (unsigned)pk;
#else
  return (unsigned)f2fp8(v0) | ((unsigned)f2fp8(v1) << 8) |
         ((unsigned)f2fp8(v2) << 16) | ((unsigned)f2fp8(v3) << 24);
#endif
}
__device__ __forceinline__ int swz8(int r) {         // fp8 chunk swizzle
  return (r ^ (r >> 2)) & 3;
}

// ---------------- weight convert f32 -> bf16 (4 matrices) + qkv bias concat ----------------
__global__ void cvt_w(const float* __restrict__ w0, const float* __restrict__ w1,
                      const float* __restrict__ w2, const float* __restrict__ w3,
                      const float* __restrict__ bq, const float* __restrict__ bk,
                      const float* __restrict__ bv,
                      unsigned short* __restrict__ out, float* __restrict__ bcat) {
  int i = blockIdx.x * 256 + threadIdx.x;
  const int n = CCH * CCH;
  if (i < CCH) {
    bcat[i]           = bq[i];
    bcat[CCH + i]     = bk[i];
    bcat[2 * CCH + i] = bv[i];
  }
  if (i < n) {
    out[i]         = f2bf(w0[i]);
    out[n + i]     = f2bf(w1[i]);
    out[2 * n + i] = f2bf(w2[i]);
    out[3 * n + i] = f2bf(w3[i]);
  }
}

// ---------------- GroupNorm stats: one block per (b,g) ----------------
__global__ void gn_stats(const float* __restrict__ x, float* __restrict__ stats) {
  const int bg = blockIdx.x;
  const float* base = x + (size_t)bg * (16 * HWP);
  float s = 0.f, sq = 0.f;
  for (int i = threadIdx.x; i < 16 * HWP / 4; i += 256) {
    float4 v = ((const float4*)base)[i];
    s += v.x + v.y + v.z + v.w;
    sq += v.x * v.x + v.y * v.y + v.z * v.z + v.w * v.w;
  }
  #pragma unroll
  for (int o = 32; o; o >>= 1) { s += __shfl_xor(s, o); sq += __shfl_xor(sq, o); }
  __shared__ float ls[4], lq[4];
  const int wv = threadIdx.x >> 6;
  if ((threadIdx.x & 63) == 0) { ls[wv] = s; lq[wv] = sq; }
  __syncthreads();
  if (threadIdx.x == 0) {
    s = ls[0] + ls[1] + ls[2] + ls[3];
    sq = lq[0] + lq[1] + lq[2] + lq[3];
    const float inv_n = 1.f / (16.f * HWP);
    float mean = s * inv_n;
    float var = sq * inv_n - mean * mean;
    stats[2 * bg] = mean;
    stats[2 * bg + 1] = rsqrtf(var + 1e-5f);
  }
}

// ---------------- GroupNorm apply + transpose -> h_t (hw, c) bf16 ----------------
__global__ void gn_apply(const float* __restrict__ x, const float* __restrict__ stats,
                         const float* __restrict__ scale, const float* __restrict__ bias,
                         unsigned short* __restrict__ ht) {
  const int p0 = blockIdx.x * 64, c0 = blockIdx.y * 64, b = blockIdx.z;
  const int tx = threadIdx.x & 63, ty = threadIdx.x >> 6;
  __shared__ unsigned short tile[64][65];
  #pragma unroll 4
  for (int j = 0; j < 16; ++j) {
    int cl = ty + j * 4;
    int c = c0 + cl;
    int g = c >> 4;
    float mean = stats[(b * NG + g) * 2];
    float rstd = stats[(b * NG + g) * 2 + 1];
    float v = x[((size_t)(b * CCH + c)) * HWP + p0 + tx];
    v = (v - mean) * rstd * scale[c] + bias[c];
    tile[cl][tx] = f2bf(v);
  }
  __syncthreads();
  #pragma unroll 4
  for (int j = 0; j < 16; ++j) {
    int pl = ty + j * 4;
    ht[((size_t)b * HWP + p0 + pl) * CCH + c0 + tx] = tile[tx][pl];
  }
}

// ---------------- NT GEMM (R3 engine): 128x128, BK=64, dbuf, bf16 MFMA ----------------
// MODE 0: fp8 out. n0<1024: Q/K -> qk8 (ldc=1024B rows). n0>=1024: V -> byte-LDS-bounce
//         transpose -> vT8 (=Res, stride sRes bytes).   (fused QKV + V^T, all fp8)
// MODE 3: f32 out, + biasRow + Res(prefetched to regs), coalesced epilogue (final proj)
template<int MODE>
__device__ __forceinline__ void gemm_body(
    const unsigned short* __restrict__ A, const unsigned short* __restrict__ Bm,
    void* __restrict__ Cm, const float* __restrict__ biasRow,
    const float* __restrict__ biasCol, const float* __restrict__ Res,
    int K, int lda, int ldb, int ldc, float scale,
    long long sA, long long sB, long long sC, long long sRes) {
  // --- bijective XCD swizzle ---
  const int nbx = gridDim.x, nby = gridDim.y;
  const int nb = nbx * nby * gridDim.z;
  int lin = (blockIdx.z * nby + blockIdx.y) * nbx + blockIdx.x;
  int bx, by, bz;
  if ((nb & 7) == 0) {
    int logical = (lin & 7) * (nb >> 3) + (lin >> 3);
    bx = logical % nbx;
    int t = logical / nbx;
    by = t % nby;
    bz = t / nby;
  } else { bx = blockIdx.x; by = blockIdx.y; bz = blockIdx.z; }

  const unsigned short* Ab = A + (size_t)bz * sA;
  const unsigned short* Bb = Bm + (size_t)bz * sB;
  const int m0 = by * 128, n0 = bx * 128;
  __shared__ __align__(16) unsigned short sm[2][2][128 * 64];  // [A/B][dbuf][tile]
  const int tid = threadIdx.x, wave = tid >> 6, lane = tid & 63;
  const int wr = (wave >> 1) * 64, wc = (wave & 1) * 64;
  const int lr = lane & 15, lkc = lane >> 4;
  f32x4 acc[4][4] = {};

  // MODE 3: prefetch the residual tile into registers (read hides under the K-loop)
  float4 xr[16];
  if (MODE == 3) {
    #pragma unroll
    for (int pass = 0; pass < 2; ++pass)
      #pragma unroll
      for (int i = 0; i < 8; ++i) {
        int idx = i * 256 + tid;
        int rrow = idx >> 5, c4 = (idx & 31) << 2;
        size_t gidx = (size_t)(m0 + pass * 64 + rrow) * ldc + (n0 + c4);
        xr[pass * 8 + i] = *(const float4*)&Res[(size_t)bz * sRes + gidx];
      }
  }

  const int chunkBase = wave * 64 + lane;
  int srow[4], sc8[4];
  #pragma unroll
  for (int it = 0; it < 4; ++it) {
    int chunk = it * 256 + chunkBase;
    srow[it] = chunk >> 3;
    sc8[it] = (((chunk & 7) ^ (srow[it] & 7)) * 8);
  }

  #define STAGE(buf, kt)                                                                 \
    { _Pragma("unroll")                                                                  \
      for (int it = 0; it < 4; ++it) {                                                   \
        __builtin_amdgcn_global_load_lds(                                                \
            (const AS1 unsigned int*)(Ab + (size_t)(m0 + srow[it]) * lda + (kt) + sc8[it]), \
            (AS3 unsigned int*)(&sm[0][buf][0] + (size_t)(it * 256 + wave * 64) * 8), 16, 0, 0); \
        __builtin_amdgcn_global_load_lds(                                                \
            (const AS1 unsigned int*)(Bb + (size_t)(n0 + srow[it]) * ldb + (kt) + sc8[it]), \
            (AS3 unsigned int*)(&sm[1][buf][0] + (size_t)(it * 256 + wave * 64) * 8), 16, 0, 0); \
      }                                                                                  \
    }

  STAGE(0, 0);
  __syncthreads();
  int cur = 0;
  for (int kt = 0; kt < K; kt += 64) {
    if (kt + 64 < K) STAGE(cur ^ 1, kt + 64);
    #pragma unroll
    for (int kk = 0; kk < 64; kk += 32) {
      const int jbase = (kk >> 3) + lkc;
      s16x8 af[4], bfv[4];
      #pragma unroll
      for (int m = 0; m < 4; ++m) {
        int r = wr + m * 16 + lr;
        af[m] = *(const s16x8*)&sm[0][cur][r * 64 + ((jbase ^ (r & 7)) << 3)];
      }
      #pragma unroll
      for (int n = 0; n < 4; ++n) {
        int r = wc + n * 16 + lr;
        bfv[n] = *(const s16x8*)&sm[1][cur][r * 64 + ((jbase ^ (r & 7)) << 3)];
      }
      #pragma unroll
      for (int m = 0; m < 4; ++m)
        #pragma unroll
        for (int n = 0; n < 4; ++n)
          acc[m][n] = __builtin_amdgcn_mfma_f32_16x16x32_bf16(af[m], bfv[n], acc[m][n], 0, 0, 0);
    }
    __syncthreads();
    cur ^= 1;
  }
  #undef STAGE

  const int r0 = (lane >> 4) * 4, ccol = lane & 15;
  if (MODE == 0) {
    if (n0 >= 1024) {
      // ---- V-block: fp8 transpose via byte LDS bounce [128][136] -> vT8 (b,c,p) ----
      unsigned char* ltb = (unsigned char*)&sm[0][0][0];  // 17408 B
      #pragma unroll
      for (int m = 0; m < 4; ++m) {
        const int gm_l = wr + m * 16 + r0;                // local p-row (mult of 4)
        #pragma unroll
        for (int n = 0; n < 4; ++n) {
          const int gn_l = wc + n * 16 + ccol;            // local o-col
          const float bc = biasCol ? biasCol[n0 + gn_l] : 0.f;
          unsigned pk = pk4_fp8(acc[m][n][0] * scale + bc, acc[m][n][1] * scale + bc,
                                acc[m][n][2] * scale + bc, acc[m][n][3] * scale + bc);
          *(unsigned*)&ltb[gn_l * 136 + gm_l] = pk;       // transposed: [o][p]
        }
      }
      __syncthreads();
      unsigned char* vout = (unsigned char*)Res;          // vT8 base
      const int c0v = n0 - 1024;
      #pragma unroll
      for (int i = 0; i < 8; ++i) {
        int idx = i * 256 + tid;
        int orow = idx >> 4, pc = (idx & 15) * 8;
        unsigned long long v8 = *(const unsigned long long*)&ltb[orow * 136 + pc];
        *(unsigned long long*)&vout[(size_t)bz * sRes + (size_t)(c0v + orow) * HWP + m0 + pc] = v8;
      }
    } else {
      // ---- Q/K block: fp8 out to qk8 (ldc bytes per p-row) ----
      unsigned char* C8 = (unsigned char*)Cm;
      #pragma unroll
      for (int m = 0; m < 4; ++m) {
        const int gm = m0 + wr + m * 16 + r0;
        #pragma unroll
        for (int n = 0; n < 4; ++n) {
          const int gn = n0 + wc + n * 16 + ccol;
          const float bc = biasCol ? biasCol[gn] : 0.f;
          unsigned pk = pk4_fp8(acc[m][n][0] * scale + bc, acc[m][n][1] * scale + bc,
                                acc[m][n][2] * scale + bc, acc[m][n][3] * scale + bc);
          #pragma unroll
          for (int r = 0; r < 4; ++r)
            C8[(size_t)bz * sC + (size_t)(gm + r) * ldc + gn] =
                (unsigned char)(pk >> (8 * r));
        }
      }
    }
  } else {
    // f32 out: coalesced epilogue via LDS bounce; residual already in xr registers
    float* ft = (float*)&sm[0][0][0];
    float* Cf = (float*)Cm;
    #pragma unroll
    for (int pass = 0; pass < 2; ++pass) {
      __syncthreads();
      if ((wave >> 1) == pass) {
        #pragma unroll
        for (int m = 0; m < 4; ++m) {
          const int rl0 = m * 16 + (lane >> 4) * 4;
          #pragma unroll
          for (int n = 0; n < 4; ++n) {
            const int cl = wc + n * 16 + (lane & 15);
            #pragma unroll
            for (int r = 0; r < 4; ++r) {
              float val = acc[m][n][r];
              if (biasRow) val += biasRow[m0 + pass * 64 + rl0 + r];
              ft[(rl0 + r) * 132 + cl] = val;
            }
          }
        }
      }
      __syncthreads();
      #pragma unroll
      for (int i = 0; i < 8; ++i) {
        int idx = i * 256 + tid;
        int rrow = idx >> 5, c4 = (idx & 31) << 2;
        float4 v = *(const float4*)&ft[rrow * 132 + c4];
        const float4 rv = xr[pass * 8 + i];
        v.x += rv.x; v.y += rv.y; v.z += rv.z; v.w += rv.w;
        size_t gidx = (size_t)(m0 + pass * 64 + rrow) * ldc + (n0 + c4);
        *(float4*)&Cf[(size_t)bz * sC + gidx] = v;
      }
    }
  }
}

#define GEMM_ARGS const unsigned short* A, const unsigned short* Bm, void* Cm,            \
                  const float* biasRow, const float* biasCol, const float* Res,            \
                  int K, int lda, int ldb, int ldc, float scale,                           \
                  long long sA, long long sB, long long sC, long long sRes
#define GEMM_PASS A, Bm, Cm, biasRow, biasCol, Res, K, lda, ldb, ldc, scale, sA, sB, sC, sRes

__global__ __launch_bounds__(256) void gemm_qkv(GEMM_ARGS) { gemm_body<0>(GEMM_PASS); }
__global__ __launch_bounds__(256) void gemm_res(GEMM_ARGS) { gemm_body<3>(GEMM_PASS); }

// ================= S-GEMM fp8: 256x128-tile, BK=64, dbuf, 8 waves, exp->fp8 epilogue =================
__global__ __launch_bounds__(512)
void gemm_s8(const unsigned char* __restrict__ A, const unsigned char* __restrict__ Bm,
             unsigned char* __restrict__ C,
             int K, int lda, int ldb, int ldc, float scale,
             long long sA, long long sB, long long sC) {
  const int nbx = gridDim.x, nby = gridDim.y;
  const int nb = nbx * nby * gridDim.z;
  int lin = (blockIdx.z * nby + blockIdx.y) * nbx + blockIdx.x;
  int bx, by, bz;
  if ((nb & 7) == 0) {
    int logical = (lin & 7) * (nb >> 3) + (lin >> 3);
    bx = logical % nbx;
    int t = logical / nbx;
    by = t % nby;
    bz = t / nby;
  } else { bx = blockIdx.x; by = blockIdx.y; bz = blockIdx.z; }

  const unsigned char* __restrict__ Ab = A + (size_t)bz * sA;
  const unsigned char* __restrict__ Bb = Bm + (size_t)bz * sB;
  unsigned char* __restrict__ Cb = C + (size_t)bz * sC;
  const int m0 = by * 256, n0 = bx * 128;

  __shared__ __align__(16) unsigned char smA[2][256 * 64];   // 32 KB
  __shared__ __align__(16) unsigned char smB[2][128 * 64];   // 16 KB

  const int tid = threadIdx.x, wave = tid >> 6, lane = tid & 63;
  const int wr = (wave >> 1) * 64;                  // 4 M-groups of 64
  const int wc = (wave & 1) * 64;                   // 2 N-groups of 64
  const int lr = lane & 15, lkc = lane >> 4;
  f32x4 acc[4][4] = {};

  // staging: A 16KB = 1024 16B-chunks -> 2/thread; B 512 chunks -> 1/thread
  int aRow[2], aCol[2];
  #pragma unroll
  for (int it = 0; it < 2; ++it) {
    int chunk = it * 512 + tid;
    int row = chunk >> 2, cc = chunk & 3;
    aRow[it] = row;
    aCol[it] = ((cc ^ swz8(row)) << 4);
  }
  const int bRow = tid >> 2;
  const int bCol = (((tid & 3) ^ swz8(bRow)) << 4);

  #define STG8(buf, kt)                                                                       \
    { _Pragma("unroll")                                                                       \
      for (int it = 0; it < 2; ++it)                                                          \
        __builtin_amdgcn_global_load_lds(                                                     \
            (const AS1 unsigned int*)(Ab + (size_t)(m0 + aRow[it]) * lda + (kt) + aCol[it]),  \
            (AS3 unsigned int*)(&smA[buf][0] + (size_t)(it * 512 + tid) * 16), 16, 0, 0);     \
      __builtin_amdgcn_global_load_lds(                                                       \
          (const AS1 unsigned int*)(Bb + (size_t)(n0 + bRow) * ldb + (kt) + bCol),            \
          (AS3 unsigned int*)(&smB[buf][0] + (size_t)tid * 16), 16, 0, 0);                    \
    }

  STG8(0, 0);
  __syncthreads();
  int cur = 0;
  for (int kt = 0; kt < K; kt += 64) {
    if (kt + 64 < K) STG8(cur ^ 1, kt + 64);
    #pragma unroll
    for (int s = 0; s < 2; ++s) {
      const int o = s * 32 + lkc * 8;
      long af[4], bfv[4];
      #pragma unroll
      for (int m = 0; m < 4; ++m) {
        int r = wr + m * 16 + lr;
        af[m] = *(const long*)&smA[cur][r * 64 + ((((o >> 4) ^ swz8(r)) << 4) | (o & 15))];
      }
      #pragma unroll
      for (int n = 0; n < 4; ++n) {
        int rb = wc + n * 16 + lr;
        bfv[n] = *(const long*)&smB[cur][rb * 64 + ((((o >> 4) ^ swz8(rb)) << 4) | (o & 15))];
      }
      #pragma unroll
      for (int m = 0; m < 4; ++m)
        #pragma unroll
        for (int n = 0; n < 4; ++n)
          acc[m][n] = __builtin_amdgcn_mfma_f32_16x16x32_fp8_fp8(af[m], bfv[n], acc[m][n], 0, 0, 0);
    }
    __syncthreads();
    cur ^= 1;
  }
  #undef STG8

  const int r0 = (lane >> 4) * 4, ccol = lane & 15;
  #pragma unroll
  for (int m = 0; m < 4; ++m) {
    const int gm = m0 + wr + m * 16 + r0;
    #pragma unroll
    for (int n = 0; n < 4; ++n) {
      const int gn = n0 + wc + n * 16 + ccol;
      unsigned pk = pk4_fp8(__expf(acc[m][n][0] * scale), __expf(acc[m][n][1] * scale),
                            __expf(acc[m][n][2] * scale), __expf(acc[m][n][3] * scale));
      #pragma unroll
      for (int r = 0; r < 4; ++r)
        Cb[(size_t)(gm + r) * ldc + gn] = (unsigned char)(pk >> (8 * r));
    }
  }
}

// ================= PV fp8: 128x256-tile, BK=64, dbuf, 8 waves, fused denominator =================
// A=P8 (4096B rows, M=4096), B=vT8 (4096B rows, N=512). BN=256 halves P8 panel re-reads.
// LDS = 2*(128+256)*64 = 48KB. 512 thr, 8 waves (2M x 4N), wave = 64x64.
__global__ __launch_bounds__(512)
void gemm_pv8(const unsigned char* __restrict__ A, const unsigned char* __restrict__ Bm,
              unsigned short* __restrict__ C,
              int K, int lda, int ldb, int ldc,
              long long sA, long long sB, long long sC) {
  const int nbx = gridDim.x, nby = gridDim.y;
  const int nb = nbx * nby * gridDim.z;
  int lin = (blockIdx.z * nby + blockIdx.y) * nbx + blockIdx.x;
  int bx, by, bz;
  if ((nb & 7) == 0) {
    int logical = (lin & 7) * (nb >> 3) + (lin >> 3);
    bx = logical % nbx;
    int t = logical / nbx;
    by = t % nby;
    bz = t / nby;
  } else { bx = blockIdx.x; by = blockIdx.y; bz = blockIdx.z; }

  const unsigned char* __restrict__ Ab = A + (size_t)bz * sA;
  const unsigned char* __restrict__ Bb = Bm + (size_t)bz * sB;
  unsigned short* __restrict__ Cb = C + (size_t)bz * sC;
  const int m0 = by * 128, n0 = bx * 256;

  __shared__ __align__(16) unsigned char pA[2][128 * 64];    // 16 KB
  __shared__ __align__(16) unsigned char pB[2][256 * 64];    // 32 KB

  const int tid = threadIdx.x, wave = tid >> 6, lane = tid & 63;
  const int wr = (wave >> 2) * 64;                  // 2 M-groups of 64
  const int wc = (wave & 3) * 64;                   // 4 N-groups of 64
  const int lr = lane & 15, lkc = lane >> 4;
  f32x4 acc[4][4] = {};
  f32x4 acc_d[4] = {};
  const long ones8 = 0x3838383838383838LL;          // 8x fp8 e4m3 1.0

  // staging: A 8KB = 512 chunks -> 1/thread; B 16KB = 1024 chunks -> 2/thread
  const int aRow = tid >> 2;
  const int aCol = (((tid & 3) ^ swz8(aRow)) << 4);
  int bRow[2], bCol[2];
  #pragma unroll
  for (int it = 0; it < 2; ++it) {
    int chunk = it * 512 + tid;
    int row = chunk >> 2, cc = chunk & 3;
    bRow[it] = row;
    bCol[it] = ((cc ^ swz8(row)) << 4);
  }

  #define STGP(buf, kt)                                                                       \
    { __builtin_amdgcn_global_load_lds(                                                       \
          (const AS1 unsigned int*)(Ab + (size_t)(m0 + aRow) * lda + (kt) + aCol),            \
          (AS3 unsigned int*)(&pA[buf][0] + (size_t)tid * 16), 16, 0, 0);                     \
      _Pragma("unroll")                                                                       \
      for (int it = 0; it < 2; ++it)                                                          \
        __builtin_amdgcn_global_load_lds(                                                     \
            (const AS1 unsigned int*)(Bb + (size_t)(n0 + bRow[it]) * ldb + (kt) + bCol[it]),  \
            (AS3 unsigned int*)(&pB[buf][0] + (size_t)(it * 512 + tid) * 16), 16, 0, 0);      \
    }

  STGP(0, 0);
  __syncthreads();
  int cur = 0;
  for (int kt = 0; kt < K; kt += 64) {
    if (kt + 64 < K) STGP(cur ^ 1, kt + 64);
    #pragma unroll
    for (int s = 0; s < 2; ++s) {
      const int o = s * 32 + lkc * 8;
      long af[4], bfv[4];
      #pragma unroll
      for (int m = 0; m < 4; ++m) {
        int r = wr + m * 16 + lr;
        af[m] = *(const long*)&pA[cur][r * 64 + ((((o >> 4) ^ swz8(r)) << 4) | (o & 15))];
      }
      #pragma unroll
      for (int n = 0; n < 4; ++n) {
        int rb = wc + n * 16 + lr;
        bfv[n] = *(const long*)&pB[cur][rb * 64 + ((((o >> 4) ^ swz8(rb)) << 4) | (o & 15))];
      }
      #pragma unroll
      for (int m = 0; m < 4; ++m) {
        #pragma unroll
        for (int n = 0; n < 4; ++n)
          acc[m][n] = __builtin_amdgcn_mfma_f32_16x16x32_fp8_fp8(af[m], bfv[n], acc[m][n], 0, 0, 0);
        acc_d[m] = __builtin_amdgcn_mfma_f32_16x16x32_fp8_fp8(af[m], ones8, acc_d[m], 0, 0, 0);
      }
    }
    __syncthreads();
    cur ^= 1;
  }
  #undef STGP

  const int r0 = (lane >> 4) * 4, ccol = lane & 15;
  #pragma unroll
  for (int m = 0; m < 4; ++m) {
    const int gm = m0 + wr + m * 16 + r0;
    const float inv0 = 1.f / acc_d[m][0];
    const float inv1 = 1.f / acc_d[m][1];
    const float inv2 = 1.f / acc_d[m][2];
    const float inv3 = 1.f / acc_d[m][3];
    #pragma unroll
    for (int n = 0; n < 4; ++n) {
      const int gn = n0 + wc + n * 16 + ccol;
      #pragma unroll
      for (int r = 0; r < 4; ++r) {
        float val = acc[m][n][r] * (r == 0 ? inv0 : r == 1 ? inv1 : r == 2 ? inv2 : inv3);
        Cb[(size_t)(gm + r) * ldc + gn] = f2bf(val);
      }
    }
  }
}

extern "C" void kernel_launch(void* const* d_in, const int* in_sizes, int n_in,
                              void* d_out, int out_size, void* d_ws, size_t ws_size,
                              hipStream_t stream) {
  (void)in_sizes; (void)n_in; (void)out_size;
  const float* x   = (const float*)d_in[0];
  const float* nsc = (const float*)d_in[1];
  const float* nbi = (const float*)d_in[2];
  const float* wq  = (const float*)d_in[3];
  const float* bq  = (const float*)d_in[4];
  const float* wk  = (const float*)d_in[5];
  const float* bk  = (const float*)d_in[6];
  const float* wv  = (const float*)d_in[7];
  const float* bv  = (const float*)d_in[8];
  const float* wp  = (const float*)d_in[9];
  const float* bp  = (const float*)d_in[10];
  float* out = (float*)d_out;
  char* ws = (char*)d_ws;

  const size_t nW = (size_t)CCH * CCH;
  unsigned short* wb = (unsigned short*)ws;            // 2 MB (bf16 weights)
  float* bcat = (float*)(ws + 4 * nW * 2);             // 6 KB
  float* stats = bcat + 1536;                          // 2 KB
  const size_t o_h = 4 * nW * 2 + 16384;
  unsigned short* ht = (unsigned short*)(ws + o_h);    // 32 MB (b, p, 512) bf16
  unsigned char* qk8 = (unsigned char*)(ht + (size_t)BATCH * HWP * CCH);   // 32 MB (b,p,1024) fp8
  unsigned char* vT8 = qk8 + (size_t)BATCH * HWP * 1024;                   // 16 MB (b,c,p) fp8
  unsigned char* P8  = vT8 + (size_t)BATCH * CCH * HWP;                    // G*16 MB (slice)
  unsigned short* ot = ht;                             // alias: ht dead after QKV gemm
  const size_t o_P8 = o_h + (size_t)BATCH * HWP * CCH * 2
                    + (size_t)BATCH * HWP * 1024 + (size_t)BATCH * CCH * HWP;
  int G = 8;
  while (G > 1 && o_P8 + (size_t)G * HWP * HWP > ws_size) G >>= 1;

  const long long sHC  = (long long)HWP * CCH;         // bf16 elements / batch
  const long long sQK8 = (long long)HWP * 1024;        // bytes / batch
  const long long sV8  = (long long)CCH * HWP;         // bytes / batch
  const long long sP8  = (long long)HWP * HWP;         // bytes / batch

  cvt_w<<<dim3((unsigned)((nW + 255) / 256)), dim3(256), 0, stream>>>(
      wq, wk, wv, wp, bq, bk, bv, wb, bcat);
  gn_stats<<<dim3(BATCH * NG), dim3(256), 0, stream>>>(x, stats);
  gn_apply<<<dim3(HWP / 64, CCH / 64, BATCH), dim3(256), 0, stream>>>(x, stats, nsc, nbi, ht);

  // fused QKV (fp8 out): Q,K -> qk8 (b,p,1024); V -> vT8 transposed (b,c,p)
  gemm_qkv<<<dim3(1536 / 128, HWP / 128, BATCH), dim3(256), 0, stream>>>(
      ht, wb, qk8, nullptr, bcat, (const float*)vT8,
      CCH, CCH, CCH, 1024, 1.f, sHC, 0, sQK8, sV8);

  const float sc = 0.04419417382415922f;               // 512^-0.5
  for (int b0 = 0; b0 < BATCH; b0 += G) {
    // P8[d][e] = fp8(exp(sc * q8[d].k8[e]))
    gemm_s8<<<dim3(HWP / 128, HWP / 256, G), dim3(512), 0, stream>>>(
        qk8 + (size_t)b0 * sQK8, qk8 + 512 + (size_t)b0 * sQK8, P8,
        CCH, 1024, 1024, HWP, sc, sQK8, sQK8, sP8);
    // ot[d][c] = (P8[d].vT8[c]) / (P8[d].1)   (BN=256: P panels re-read 2x not 4x)
    gemm_pv8<<<dim3(CCH / 256, HWP / 128, G), dim3(512), 0, stream>>>(
        P8, vT8 + (size_t)b0 * sV8, ot + (size_t)b0 * sHC,
        HWP, HWP, HWP, CCH, sP8, sV8, sHC);
  }

  // final: out[o][p] = x[o][p] + bp[o] + sum_c wp[o][c] ot[p][c]   (bf16 engine, f32 out)
  gemm_res<<<dim3(HWP / 128, CCH / 128, BATCH), dim3(256), 0, stream>>>(
      wb + 3 * nW, ot, out, bp, nullptr, x,
      CCH, CCH, CCH, HWP, 1.f, 0, sHC, sHC, sHC);
}